// Round 8
// baseline (423.979 us; speedup 1.0000x reference)
//
#include <hip/hip_runtime.h>
#include <hip/hip_bf16.h>
#include <stdint.h>

#define XS 128
#define YS 128
#define ZS 8
#define NQ (XS*YS*ZS)        // 131072 queries
#define CDIM 128
#define NH 8
#define HD 16
#define DH 192
#define DW 640
#define NPIX (DH*DW)
#define NVPIX 10080          // 7680 + 1920 + 480

typedef float f32x4 __attribute__((ext_vector_type(4)));
typedef short s16x8 __attribute__((ext_vector_type(8)));

__device__ __forceinline__ float b2f(unsigned short u){
    union { unsigned int i; float f; } v; v.i = ((unsigned int)u) << 16; return v.f;
}
__device__ __forceinline__ unsigned short f2b(float f){
    __hip_bfloat16 h = __float2bfloat16(f);
    return *reinterpret_cast<unsigned short*>(&h);
}
__device__ __forceinline__ float blo(unsigned int u){
    union { unsigned int i; float f; } v; v.i = u << 16; return v.f;
}
__device__ __forceinline__ float bhi(unsigned int u){
    union { unsigned int i; float f; } v; v.i = u & 0xffff0000u; return v.f;
}

// ------------- inverse of K/E (1 thread) + Woff/Wattw/Wout -> bf16 (padded) -------------
// Wbf layout: [0,24576) Woff | [24576,36864) Wattw | [36864,40960) zero pad (tiles 18,19)
//             [40960,57344) Wout
__global__ __launch_bounds__(256)
void inv_kernel(const float* __restrict__ K,
                const float* __restrict__ E,
                double* __restrict__ inv_out,
                const float* __restrict__ Woff,
                const float* __restrict__ Wattw,
                const float* __restrict__ Wout,
                unsigned short* __restrict__ Wbf){
    if (blockIdx.x != 0){
        int idx = (blockIdx.x-1)*256 + threadIdx.x;
        if (idx < 24576)      Wbf[idx] = f2b(Woff[idx]);
        else if (idx < 36864) Wbf[idx] = f2b(Wattw[idx-24576]);
        else if (idx < 40960) Wbf[idx] = 0;
        else if (idx < 57344) Wbf[idx] = f2b(Wout[idx-40960]);
        return;
    }
    if (threadIdx.x != 0) return;
    double k[3][3], e[4][4];
    for (int i=0;i<9;i++)  k[i/3][i%3] = (double)K[i];
    for (int i=0;i<16;i++) e[i/4][i%4] = (double)E[i];
    double det = k[0][0]*(k[1][1]*k[2][2]-k[1][2]*k[2][1])
               - k[0][1]*(k[1][0]*k[2][2]-k[1][2]*k[2][0])
               + k[0][2]*(k[1][0]*k[2][1]-k[1][1]*k[2][0]);
    double id = 1.0/det;
    double inv[3][3];
    inv[0][0]=(k[1][1]*k[2][2]-k[1][2]*k[2][1])*id;
    inv[0][1]=(k[0][2]*k[2][1]-k[0][1]*k[2][2])*id;
    inv[0][2]=(k[0][1]*k[1][2]-k[0][2]*k[1][1])*id;
    inv[1][0]=(k[1][2]*k[2][0]-k[1][0]*k[2][2])*id;
    inv[1][1]=(k[0][0]*k[2][2]-k[0][2]*k[2][0])*id;
    inv[1][2]=(k[0][2]*k[1][0]-k[0][0]*k[1][2])*id;
    inv[2][0]=(k[1][0]*k[2][1]-k[1][1]*k[2][0])*id;
    inv[2][1]=(k[0][1]*k[2][0]-k[0][0]*k[2][1])*id;
    inv[2][2]=(k[0][0]*k[1][1]-k[0][1]*k[1][0])*id;
    for (int i=0;i<9;i++) inv_out[i] = inv[i/3][i%3];
    double a[4][8];
    for (int i=0;i<4;i++){ for(int j=0;j<4;j++){ a[i][j]=e[i][j]; a[i][4+j]=(i==j)?1.0:0.0; } }
    for (int c=0;c<4;c++){
        int piv=c; double best=fabs(a[c][c]);
        for (int r=c+1;r<4;r++){ double v=fabs(a[r][c]); if (v>best){best=v;piv=r;} }
        if (piv!=c){ for (int j=0;j<8;j++){ double tmp=a[c][j]; a[c][j]=a[piv][j]; a[piv][j]=tmp; } }
        double pv = 1.0/a[c][c];
        for (int j=0;j<8;j++) a[c][j]*=pv;
        for (int r=0;r<4;r++){
            if (r==c) continue;
            double f=a[r][c];
            for(int j=0;j<8;j++) a[r][j]-=f*a[c][j];
        }
    }
    for (int i=0;i<16;i++) inv_out[9+i] = a[i/4][4 + (i%4)];
}

// ====== fused prep: offaw MFMA GEMM(+softmax) | value GEMM | mask, role-split ======
// offaw role LDS: Ob[8][288][8] u16 (36864, ALIASES qbf[64][128]bf16 swz 16384)
//                 + bias[288] f32 @36864 (1152). Total 38016 -> 4 blocks/CU.
__global__ __launch_bounds__(256)
void prep_kernel(const float* __restrict__ q_in,          // chunk base
                 const unsigned short* __restrict__ Wbf,  // [320][128] bf16 (padded)
                 const float* __restrict__ boff,
                 const float* __restrict__ battw,
                 unsigned short* __restrict__ offawB,     // [len/8][288][8]
                 int nOff, int nVal,
                 const float* __restrict__ f0,
                 const float* __restrict__ f1,
                 const float* __restrict__ f2,
                 const float* __restrict__ Wv,
                 const float* __restrict__ bv,
                 unsigned short* __restrict__ value,      // [NH][NVPIX][HD]
                 const float* __restrict__ depth,
                 const double* __restrict__ invm,
                 const float* __restrict__ vorigin,
                 unsigned char* __restrict__ mask){
    __shared__ __align__(16) unsigned char smem[38016];
    const int t = threadIdx.x;

    if ((int)blockIdx.x < nOff){
        unsigned short* Ob   = (unsigned short*)smem;       // 36864 (after MFMA)
        unsigned char*  qbfB = smem;                        // 16384 (before/during MFMA)
        float*          bias = (float*)(smem + 36864);      // 1152
        const int n0 = blockIdx.x * 64;

        // ---- stage q: coalesced float4 -> bf16 pairs, XOR-swizzled rows ----
        #pragma unroll
        for (int i=0;i<8;i++){
            int idx = t + i*256;              // 2048 float4s = 64 rows x 32
            int row = idx >> 5, c4 = idx & 31;
            float4 qv = ((const float4*)(q_in + (size_t)(n0+row)*CDIM))[c4];
            unsigned int pk0 = (unsigned int)f2b(qv.x) | ((unsigned int)f2b(qv.y)<<16);
            unsigned int pk1 = (unsigned int)f2b(qv.z) | ((unsigned int)f2b(qv.w)<<16);
            unsigned int bo = ((unsigned int)(row*256 + c4*8)) ^ (unsigned int)((row&7)<<4);
            *(unsigned int*)(qbfB + bo)     = pk0;
            *(unsigned int*)(qbfB + bo + 4) = pk1;
        }
        for (int i=t;i<288;i+=256) bias[i] = (i<192)? boff[i] : battw[i-192];
        __syncthreads();

        // ---- MFMA: 5 feature tiles x 4 query tiles per wave ----
        const int w = t >> 6, lane = t & 63, lr = lane & 15, lg = lane >> 4;
        const int nt0 = w*5;
        f32x4 acc[5][4];
        #pragma unroll
        for (int j=0;j<5;j++)
            #pragma unroll
            for (int qt=0;qt<4;qt++) acc[j][qt] = (f32x4){0.f,0.f,0.f,0.f};

        #pragma unroll
        for (int ks=0; ks<4; ++ks){
            s16x8 bf[4];
            #pragma unroll
            for (int qt=0;qt<4;qt++){
                int qrow = qt*16 + lr;
                unsigned int bo = ((unsigned int)(qrow*256 + ks*64 + lg*16)) ^ (unsigned int)((qrow&7)<<4);
                bf[qt] = *(const s16x8*)(qbfB + bo);
            }
            const unsigned short* wp = Wbf + (size_t)(nt0*16 + lr)*CDIM + ks*32 + lg*8;
            #pragma unroll
            for (int j=0;j<5;++j){
                s16x8 af = *(const s16x8*)(wp + j*16*CDIM);
                #pragma unroll
                for (int qt=0;qt<4;qt++)
                    acc[j][qt] = __builtin_amdgcn_mfma_f32_16x16x32_bf16(af, bf[qt], acc[j][qt], 0, 0, 0);
            }
        }
        __syncthreads();   // all waves done reading qbf before Ob overwrites it

        // ---- writeback + bias into Ob[q>>3][f][q&7] ----
        #pragma unroll
        for (int j=0;j<5;++j){
            int nt = nt0 + j;
            if (nt < 18){
                #pragma unroll
                for (int qt=0;qt<4;qt++){
                    int q = qt*16 + lr;
                    int base = (q>>3)*2304 + (q&7);
                    #pragma unroll
                    for (int r=0;r<4;++r){
                        int f = nt*16 + lg*4 + r;
                        Ob[base + f*8] = f2b(acc[j][qt][r] + bias[f]);
                    }
                }
            }
        }
        __syncthreads();

        // ---- softmax over 12 logits per (query, head): 512 tasks ----
        for (int task = t; task < 512; task += 256){
            int q = task >> 3, h = task & 7;
            unsigned short* p = Ob + (q>>3)*2304 + (192 + h*12)*8 + (q&7);
            float e[12]; float m = -1e30f;
            #pragma unroll
            for (int i=0;i<12;i++){ e[i] = b2f(p[i*8]); m = fmaxf(m, e[i]); }
            float s = 0.f;
            #pragma unroll
            for (int i=0;i<12;i++){ e[i] = __expf(e[i]-m); s += e[i]; }
            float is = 1.f/s;
            #pragma unroll
            for (int i=0;i<12;i++) p[i*8] = f2b(e[i]*is);
        }
        __syncthreads();

        // ---- coalesced dump ----
        {
            const uint4* src = (const uint4*)Ob;
            uint4* dst = (uint4*)(offawB + (size_t)blockIdx.x * 18432);
            for (int idx = t; idx < 2304; idx += 256) dst[idx] = src[idx];
        }
    } else if ((int)blockIdx.x < nOff + nVal){
        // ---------- value: 8 pixels per block (two 128-thread halves) ----------
        const int half = t >> 7, tt = t & 127;
        const int p0 = (blockIdx.x - nOff)*8 + half*4;
        float (*fl)[4] = (float(*)[4])(smem + half*2048);
        const float* src; int hw, lp;
        if (p0 < 7680)      { src=f0; hw=7680; lp=p0; }
        else if (p0 < 9600) { src=f1; hw=1920; lp=p0-7680; }
        else                { src=f2; hw=480;  lp=p0-9600; }
        float4 v = *(const float4*)(src + tt*hw + lp);
        fl[tt][0]=v.x; fl[tt][1]=v.y; fl[tt][2]=v.z; fl[tt][3]=v.w;
        __syncthreads();
        float bb = bv[tt];
        float acc[4] = {bb,bb,bb,bb};
        const float4* wrow = (const float4*)(Wv + tt*CDIM);
        #pragma unroll 8
        for (int kc=0; kc<32; ++kc){
            float4 w = wrow[kc];
            #pragma unroll
            for (int u=0;u<4;u++){
                float wu = (u==0)?w.x:(u==1)?w.y:(u==2)?w.z:w.w;
                float4 fv = *(const float4*)fl[kc*4+u];
                acc[0] += fv.x*wu; acc[1] += fv.y*wu; acc[2] += fv.z*wu; acc[3] += fv.w*wu;
            }
        }
        const int hh = tt >> 4, cc = tt & 15;
        #pragma unroll
        for (int i=0;i<4;i++)
            value[((size_t)hh*NVPIX + (size_t)(p0+i))*HD + cc] = f2b(acc[i]);
    } else {
        // ---------- mask ----------
        int tid = (blockIdx.x - nOff - nVal)*256 + t;
        if (tid >= NPIX) return;
        int gx = tid % DW, gy = tid / DW;
        double d  = (double)depth[tid];
        double X0 = (double)gx * d, X1 = (double)gy * d, X2 = d;
        double c0 = invm[0]*X0 + invm[1]*X1 + invm[2]*X2;
        double c1 = invm[3]*X0 + invm[4]*X1 + invm[5]*X2;
        double c2 = invm[6]*X0 + invm[7]*X1 + invm[8]*X2;
        const double* iE = invm + 9;
        double w0 = iE[0]*c0 + iE[1]*c1 + iE[2]*c2  + iE[3];
        double w1 = iE[4]*c0 + iE[5]*c1 + iE[6]*c2  + iE[7];
        double w2 = iE[8]*c0 + iE[9]*c1 + iE[10]*c2 + iE[11];
        double v0 = (w0-(double)vorigin[0])/0.4 - 0.5;
        double v1 = (w1-(double)vorigin[1])/0.4 - 0.5;
        double v2 = ((w2-(double)vorigin[2])/0.4 - 0.5) / 2.0;
        int xi = (int)v0, yi = (int)v1, zi = (int)v2;
        if (xi>=0 && xi<XS && yi>=0 && yi<YS && zi>=0 && zi<ZS)
            mask[(xi*YS + yi)*ZS + zi] = 1;
    }
}

// ---------------- sampling + Wout(MFMA) + LN + mask + transposed store ----------------
__global__ __launch_bounds__(256, 2)
void attn_kernel(const float* __restrict__ q_in,
                 const float* __restrict__ refpix,
                 const unsigned short* __restrict__ offawB, // [len/8][288][8], chunk-local
                 const unsigned short* __restrict__ value,  // [NH][NVPIX][HD]
                 const unsigned short* __restrict__ WoutBf, // [128][128] bf16
                 const float* __restrict__ bout,
                 const float* __restrict__ lng,
                 const float* __restrict__ lnb,
                 const unsigned char* __restrict__ mask,
                 float* __restrict__ dout,
                 int q0g){
    const int n0l = blockIdx.x * 8;         // chunk-local
    const int n0g = q0g + n0l;              // global query index
    const int t = threadIdx.x;
    __shared__ __align__(16) unsigned char smem[25296];
    unsigned short* raw   = (unsigned short*)(smem);
    unsigned char*  descB = smem + 4608;
    float*          out2  = (float*)(smem + 4608);          // alias over desc
    unsigned char*  obfB  = smem + 16896;
    float (*q_s)[CDIM]    = (float(*)[CDIM])(smem + 20992);
    float*          rp_s  = (float*)(smem + 25088);
    float*          wredp = (float*)(smem + 25152);         // [2][4][4]
    unsigned char*  mask_s= (unsigned char*)(smem + 25280);

    // ---- stage ----
    {
        const unsigned int* src = (const unsigned int*)(offawB + (size_t)(n0l>>3)*2304);
        unsigned int* dst = (unsigned int*)raw;
        #pragma unroll
        for (int i=0;i<5;i++){ int idx = t + i*256; if (idx < 1152) dst[idx] = src[idx]; }
        ((float4*)q_s)[t] = ((const float4*)(q_in + (size_t)n0g*CDIM))[t];
        ((unsigned int*)obfB)[512 + t] = 0;   // zero obf rows 8..15
        ((unsigned int*)obfB)[768 + t] = 0;
        if (t < 16) rp_s[t] = refpix[n0g*2 + t];
        if (t < 8)  mask_s[t] = mask[n0g + t];
    }
    __syncthreads();

    // ---- Phase A: 768 sample descriptors ----
    for (int idx = t; idx < 768; idx += 256){
        int q = idx & 7, hp = idx >> 3;
        int lp = hp % 12;
        float fw, fh; int Wl, Hl, st;
        if (lp < 4)      { fw=160.f; fh=48.f; Wl=160; Hl=48; st=0; }
        else if (lp < 8) { fw=80.f;  fh=24.f; Wl=80;  Hl=24; st=7680; }
        else             { fw=40.f;  fh=12.f; Wl=40;  Hl=12; st=9600; }
        float offx = b2f(raw[(hp*2)*8 + q]);
        float offy = b2f(raw[(hp*2+1)*8 + q]);
        float aw   = b2f(raw[(192+hp)*8 + q]);
        float x = rp_s[q*2+0]*fw - 0.5f + offx;
        float y = rp_s[q*2+1]*fh - 0.5f + offy;
        float x0f = floorf(x), y0f = floorf(y);
        float lx = x-x0f, ly = y-y0f;
        int x0 = (int)x0f, y0 = (int)y0f;
        bool x0ok = (x0>=0)&&(x0<Wl), x1ok=(x0+1>=0)&&(x0+1<Wl);
        bool y0ok = (y0>=0)&&(y0<Hl), y1ok=(y0+1>=0)&&(y0+1<Hl);
        float w00 = (x0ok&&y0ok)? (1.f-lx)*(1.f-ly)*aw : 0.f;
        float w01 = (x1ok&&y0ok)? lx*(1.f-ly)*aw       : 0.f;
        float w10 = (x0ok&&y1ok)? (1.f-lx)*ly*aw       : 0.f;
        float w11 = (x1ok&&y1ok)? lx*ly*aw             : 0.f;
        int yc0 = min(max(y0,0),Hl-1), yc1 = min(max(y0+1,0),Hl-1);
        int xc0 = min(max(x0,0),Wl-1), xc1 = min(max(x0+1,0),Wl-1);
        unsigned int rb0 = (unsigned int)(st + yc0*Wl), rb1 = (unsigned int)(st + yc1*Wl);
        uint4 d;
        d.x = (rb0+(unsigned int)xc0) | ((rb0+(unsigned int)xc1)<<16);
        d.y = (rb1+(unsigned int)xc0) | ((rb1+(unsigned int)xc1)<<16);
        d.z = (unsigned int)f2b(w00) | ((unsigned int)f2b(w01)<<16);
        d.w = (unsigned int)f2b(w10) | ((unsigned int)f2b(w11)<<16);
        *(uint4*)(descB + (((unsigned int)(idx ^ ((idx>>5)&7)))<<4)) = d;
    }
    __syncthreads();

    // ---- sampling: 6 groups x 4 samples, batched unconditional gathers ----
    {
        const int cp = t & 7, hs = (t>>3) & 7, qgs = t >> 6;
        const unsigned short* vh = value + ((size_t)hs*NVPIX)*HD + cp*2;
        float av0x=0.f, av0y=0.f, av1x=0.f, av1y=0.f;
        #pragma unroll
        for (int g=0; g<6; ++g){
            uint4 d[4];
            #pragma unroll
            for (int s=0;s<4;s++){
                int lp = g*2 + (s>>1), qi2 = s&1;
                int idx = (hs*12+lp)*8 + qgs*2 + qi2;
                d[s] = *(const uint4*)(descB + (((unsigned int)(idx ^ ((idx>>5)&7)))<<4));
            }
            unsigned int u[4][4];
            #pragma unroll
            for (int s=0;s<4;s++){
                u[s][0] = *(const unsigned int*)(vh + ((size_t)(d[s].x & 0xffffu)<<4));
                u[s][1] = *(const unsigned int*)(vh + ((size_t)(d[s].x >> 16)<<4));
                u[s][2] = *(const unsigned int*)(vh + ((size_t)(d[s].y & 0xffffu)<<4));
                u[s][3] = *(const unsigned int*)(vh + ((size_t)(d[s].y >> 16)<<4));
            }
            #pragma unroll
            for (int s=0;s<4;s++){
                float w00 = blo(d[s].z), w01 = bhi(d[s].z), w10 = blo(d[s].w), w11 = bhi(d[s].w);
                float sx = blo(u[s][0])*w00 + blo(u[s][1])*w01 + blo(u[s][2])*w10 + blo(u[s][3])*w11;
                float sy = bhi(u[s][0])*w00 + bhi(u[s][1])*w01 + bhi(u[s][2])*w10 + bhi(u[s][3])*w11;
                if ((s&1)==0){ av0x += sx; av0y += sy; }
                else         { av1x += sx; av1y += sy; }
            }
        }
        const int q0q = qgs*2;
        unsigned int pk0 = (unsigned int)f2b(av0x) | ((unsigned int)f2b(av0y)<<16);
        unsigned int pk1 = (unsigned int)f2b(av1x) | ((unsigned int)f2b(av1y)<<16);
        unsigned int bo0 = (unsigned int)(q0q*256 + hs*32 + cp*4)     ^ (unsigned int)((q0q&7)<<4);
        unsigned int bo1 = (unsigned int)((q0q+1)*256 + hs*32 + cp*4) ^ (unsigned int)(((q0q+1)&7)<<4);
        *(unsigned int*)(obfB + bo0) = pk0;
        *(unsigned int*)(obfB + bo1) = pk1;
    }
    __syncthreads();

    // ---- Wout projection via MFMA, bout folded ----
    {
        const int w = t >> 6, lane = t & 63, lr = lane & 15, lg = lane >> 4;
        f32x4 a0 = (f32x4){0.f,0.f,0.f,0.f};
        f32x4 a1 = (f32x4){0.f,0.f,0.f,0.f};
        #pragma unroll
        for (int ks=0; ks<4; ++ks){
            unsigned int bo = (unsigned int)(lr*256 + ks*64 + lg*16) ^ (unsigned int)((lr&7)<<4);
            s16x8 bfrag = *(const s16x8*)(obfB + bo);
            const unsigned short* wp = WoutBf + (size_t)(w*32 + lr)*CDIM + ks*32 + lg*8;
            s16x8 af0 = *(const s16x8*)(wp);
            s16x8 af1 = *(const s16x8*)(wp + 16*CDIM);
            a0 = __builtin_amdgcn_mfma_f32_16x16x32_bf16(af0, bfrag, a0, 0, 0, 0);
            a1 = __builtin_amdgcn_mfma_f32_16x16x32_bf16(af1, bfrag, a1, 0, 0, 0);
        }
        if (lr < 8){
            int f0 = w*32 + lg*4;
            float4 b0 = *(const float4*)(bout + f0);
            float4 b1 = *(const float4*)(bout + f0 + 16);
            float4 v0, v1;
            v0.x = a0[0]+b0.x; v0.y = a0[1]+b0.y; v0.z = a0[2]+b0.z; v0.w = a0[3]+b0.w;
            v1.x = a1[0]+b1.x; v1.y = a1[1]+b1.y; v1.z = a1[2]+b1.z; v1.w = a1[3]+b1.w;
            *(float4*)(out2 + lr*CDIM + f0)      = v0;
            *(float4*)(out2 + lr*CDIM + f0 + 16) = v1;
        }
    }
    __syncthreads();

    // ---- residual + LayerNorm + mask + transposed store ----
    const int r = t & 127;
    const int qb = t >> 7;
    const int wv = t >> 6;
    float acc[4];
    #pragma unroll
    for (int qi4=0;qi4<4;qi4++) acc[qi4] = out2[(qb*4+qi4)*CDIM + r];

    float hv[4], sred[4];
    #pragma unroll
    for (int qi4=0;qi4<4;qi4++){ hv[qi4] = q_s[qb*4+qi4][r] + acc[qi4]; sred[qi4]=hv[qi4]; }
    #pragma unroll
    for (int off=32; off>0; off>>=1)
        #pragma unroll
        for (int qi4=0;qi4<4;qi4++) sred[qi4] += __shfl_xor(sred[qi4], off, 64);
    if ((t&63)==0){
        #pragma unroll
        for (int qi4=0;qi4<4;qi4++) wredp[0*16 + wv*4 + qi4]=sred[qi4];
    }
    __syncthreads();
    float mu[4], dv[4];
    #pragma unroll
    for (int qi4=0;qi4<4;qi4++){
        mu[qi4] = (wredp[0*16 + (qb*2)*4 + qi4]+wredp[0*16 + (qb*2+1)*4 + qi4]) * (1.f/128.f);
        dv[qi4] = hv[qi4]-mu[qi4];
        sred[qi4] = dv[qi4]*dv[qi4];
    }
    #pragma unroll
    for (int off=32; off>0; off>>=1)
        #pragma unroll
        for (int qi4=0;qi4<4;qi4++) sred[qi4] += __shfl_xor(sred[qi4], off, 64);
    if ((t&63)==0){
        #pragma unroll
        for (int qi4=0;qi4<4;qi4++) wredp[1*16 + wv*4 + qi4]=sred[qi4];
    }
    __syncthreads();

    float res[4];
    const float g = lng[r], b = lnb[r];
    #pragma unroll
    for (int qi4=0;qi4<4;qi4++){
        float var = (wredp[1*16 + (qb*2)*4 + qi4]+wredp[1*16 + (qb*2+1)*4 + qi4]) * (1.f/128.f);
        float nv  = dv[qi4] * __frsqrt_rn(var + 1e-5f) * g + b;
        res[qi4] = mask_s[qb*4+qi4] ? nv : q_s[qb*4+qi4][r];
    }
    float4 o; o.x=res[0]; o.y=res[1]; o.z=res[2]; o.w=res[3];
    *(float4*)(dout + (size_t)r*NQ + n0g + qb*4) = o;
}

extern "C" void kernel_launch(void* const* d_in, const int* in_sizes, int n_in,
                              void* d_out, int out_size, void* d_ws, size_t ws_size,
                              hipStream_t stream){
    const float* scene  = (const float*)d_in[0];
    const float* f0     = (const float*)d_in[1];
    const float* f1     = (const float*)d_in[2];
    const float* f2     = (const float*)d_in[3];
    const float* depth  = (const float*)d_in[4];
    const float* K      = (const float*)d_in[5];
    const float* E      = (const float*)d_in[6];
    const float* vorig  = (const float*)d_in[7];
    const float* refpix = (const float*)d_in[8];
    const float* Wv     = (const float*)d_in[9];
    const float* bv     = (const float*)d_in[10];
    const float* Woff   = (const float*)d_in[11];
    const float* boff   = (const float*)d_in[12];
    const float* Wattw  = (const float*)d_in[13];
    const float* battw  = (const float*)d_in[14];
    const float* Wout   = (const float*)d_in[15];
    const float* bout   = (const float*)d_in[16];
    const float* lng    = (const float*)d_in[17];
    const float* lnb    = (const float*)d_in[18];

    char* ws = (char*)d_ws;
    // invm(512) + mask(131072) + value(2580480) + Wbf(114688) + offawB(rest)
    const size_t FIXED = 512 + 131072 + 2580480 + 114688;
    double*         invm   = (double*)(ws);
    unsigned char*  mask   = (unsigned char*)(ws + 512);
    unsigned short* value  = (unsigned short*)(ws + 512 + 131072);
    unsigned short* Wbf    = (unsigned short*)(ws + 512 + 131072 + 2580480);
    unsigned short* WoutBf = Wbf + 40960;
    unsigned short* offawB = (unsigned short*)(ws + FIXED);

    size_t avail = (ws_size > FIXED) ? (ws_size - FIXED) : 0;
    long long maxq = (long long)(avail / (288*2));
    int chunk = (int)((maxq/64)*64);
    if (chunk > NQ) chunk = NQ;
    if (chunk < 64) chunk = 64;

    hipMemsetAsync(mask, 0, NQ, stream);
    inv_kernel<<<225, 256, 0, stream>>>(K, E, invm, Woff, Wattw, Wout, Wbf);

    for (int q0 = 0; q0 < NQ; q0 += chunk){
        int len = (NQ - q0 < chunk) ? (NQ - q0) : chunk;
        int nOff  = len/64;
        int nVal  = (q0 == 0) ? (NVPIX/8) : 0;          // 1260
        int nMask = (q0 == 0) ? ((NPIX+255)/256) : 0;   // 480
        prep_kernel<<<nOff + nVal + nMask, 256, 0, stream>>>(
            scene + (size_t)q0*CDIM, Wbf, boff, battw, offawB,
            nOff, nVal,
            f0, f1, f2, Wv, bv, value,
            depth, invm, vorig, mask);
        attn_kernel<<<len/8, 256, 0, stream>>>(scene, refpix, offawB, value,
                                               WoutBf, bout, lng, lnb, mask,
                                               (float*)d_out, q0);
    }
}

// Round 9
// 422.527 us; speedup vs baseline: 1.0034x; 1.0034x over previous
//
#include <hip/hip_runtime.h>
#include <hip/hip_bf16.h>
#include <stdint.h>

#define XS 128
#define YS 128
#define ZS 8
#define NQ (XS*YS*ZS)        // 131072 queries
#define CDIM 128
#define NH 8
#define HD 16
#define DH 192
#define DW 640
#define NPIX (DH*DW)
#define NVPIX 10080          // 7680 + 1920 + 480

typedef float f32x4 __attribute__((ext_vector_type(4)));
typedef short s16x8 __attribute__((ext_vector_type(8)));

__device__ __forceinline__ float b2f(unsigned short u){
    union { unsigned int i; float f; } v; v.i = ((unsigned int)u) << 16; return v.f;
}
__device__ __forceinline__ unsigned short f2b(float f){
    __hip_bfloat16 h = __float2bfloat16(f);
    return *reinterpret_cast<unsigned short*>(&h);
}
__device__ __forceinline__ float blo(unsigned int u){
    union { unsigned int i; float f; } v; v.i = u << 16; return v.f;
}
__device__ __forceinline__ float bhi(unsigned int u){
    union { unsigned int i; float f; } v; v.i = u & 0xffff0000u; return v.f;
}

// ------------- inverse of K/E (1 thread) + Woff/Wattw/Wout -> bf16 (padded) -------------
// Wbf layout: [0,24576) Woff | [24576,36864) Wattw | [36864,40960) zero pad (tiles 18,19)
//             [40960,57344) Wout
__global__ __launch_bounds__(256)
void inv_kernel(const float* __restrict__ K,
                const float* __restrict__ E,
                double* __restrict__ inv_out,
                const float* __restrict__ Woff,
                const float* __restrict__ Wattw,
                const float* __restrict__ Wout,
                unsigned short* __restrict__ Wbf){
    if (blockIdx.x != 0){
        int idx = (blockIdx.x-1)*256 + threadIdx.x;
        if (idx < 24576)      Wbf[idx] = f2b(Woff[idx]);
        else if (idx < 36864) Wbf[idx] = f2b(Wattw[idx-24576]);
        else if (idx < 40960) Wbf[idx] = 0;
        else if (idx < 57344) Wbf[idx] = f2b(Wout[idx-40960]);
        return;
    }
    if (threadIdx.x != 0) return;
    double k[3][3], e[4][4];
    for (int i=0;i<9;i++)  k[i/3][i%3] = (double)K[i];
    for (int i=0;i<16;i++) e[i/4][i%4] = (double)E[i];
    double det = k[0][0]*(k[1][1]*k[2][2]-k[1][2]*k[2][1])
               - k[0][1]*(k[1][0]*k[2][2]-k[1][2]*k[2][0])
               + k[0][2]*(k[1][0]*k[2][1]-k[1][1]*k[2][0]);
    double id = 1.0/det;
    double inv[3][3];
    inv[0][0]=(k[1][1]*k[2][2]-k[1][2]*k[2][1])*id;
    inv[0][1]=(k[0][2]*k[2][1]-k[0][1]*k[2][2])*id;
    inv[0][2]=(k[0][1]*k[1][2]-k[0][2]*k[1][1])*id;
    inv[1][0]=(k[1][2]*k[2][0]-k[1][0]*k[2][2])*id;
    inv[1][1]=(k[0][0]*k[2][2]-k[0][2]*k[2][0])*id;
    inv[1][2]=(k[0][2]*k[1][0]-k[0][0]*k[1][2])*id;
    inv[2][0]=(k[1][0]*k[2][1]-k[1][1]*k[2][0])*id;
    inv[2][1]=(k[0][1]*k[2][0]-k[0][0]*k[2][1])*id;
    inv[2][2]=(k[0][0]*k[1][1]-k[0][1]*k[1][0])*id;
    for (int i=0;i<9;i++) inv_out[i] = inv[i/3][i%3];
    double a[4][8];
    for (int i=0;i<4;i++){ for(int j=0;j<4;j++){ a[i][j]=e[i][j]; a[i][4+j]=(i==j)?1.0:0.0; } }
    for (int c=0;c<4;c++){
        int piv=c; double best=fabs(a[c][c]);
        for (int r=c+1;r<4;r++){ double v=fabs(a[r][c]); if (v>best){best=v;piv=r;} }
        if (piv!=c){ for (int j=0;j<8;j++){ double tmp=a[c][j]; a[c][j]=a[piv][j]; a[piv][j]=tmp; } }
        double pv = 1.0/a[c][c];
        for (int j=0;j<8;j++) a[c][j]*=pv;
        for (int r=0;r<4;r++){
            if (r==c) continue;
            double f=a[r][c];
            for(int j=0;j<8;j++) a[r][j]-=f*a[c][j];
        }
    }
    for (int i=0;i<16;i++) inv_out[9+i] = a[i/4][4 + (i%4)];
}

// ====== fused prep: offaw MFMA GEMM(+softmax) | value GEMM | mask, role-split ======
// offaw role LDS: Ob[8][288][8] u16 (36864, ALIASES qbf[64][128]bf16 swz 16384)
//                 + bias[288] f32 @36864 (1152). Total 38016 -> 4 blocks/CU.
__global__ __launch_bounds__(256)
void prep_kernel(const float* __restrict__ q_in,          // chunk base
                 const unsigned short* __restrict__ Wbf,  // [320][128] bf16 (padded)
                 const float* __restrict__ boff,
                 const float* __restrict__ battw,
                 unsigned short* __restrict__ offawB,     // [len/8][288][8]
                 int nOff, int nVal,
                 const float* __restrict__ f0,
                 const float* __restrict__ f1,
                 const float* __restrict__ f2,
                 const float* __restrict__ Wv,
                 const float* __restrict__ bv,
                 unsigned short* __restrict__ value,      // [NH][NVPIX][HD]
                 const float* __restrict__ depth,
                 const double* __restrict__ invm,
                 const float* __restrict__ vorigin,
                 unsigned char* __restrict__ mask){
    __shared__ __align__(16) unsigned char smem[38016];
    const int t = threadIdx.x;

    if ((int)blockIdx.x < nOff){
        unsigned short* Ob   = (unsigned short*)smem;       // 36864 (after MFMA)
        unsigned char*  qbfB = smem;                        // 16384 (before/during MFMA)
        float*          bias = (float*)(smem + 36864);      // 1152
        const int n0 = blockIdx.x * 64;

        // ---- stage q: coalesced float4 -> bf16 pairs, XOR-swizzled rows ----
        #pragma unroll
        for (int i=0;i<8;i++){
            int idx = t + i*256;              // 2048 float4s = 64 rows x 32
            int row = idx >> 5, c4 = idx & 31;
            float4 qv = ((const float4*)(q_in + (size_t)(n0+row)*CDIM))[c4];
            unsigned int pk0 = (unsigned int)f2b(qv.x) | ((unsigned int)f2b(qv.y)<<16);
            unsigned int pk1 = (unsigned int)f2b(qv.z) | ((unsigned int)f2b(qv.w)<<16);
            unsigned int bo = ((unsigned int)(row*256 + c4*8)) ^ (unsigned int)((row&7)<<4);
            *(unsigned int*)(qbfB + bo)     = pk0;
            *(unsigned int*)(qbfB + bo + 4) = pk1;
        }
        for (int i=t;i<288;i+=256) bias[i] = (i<192)? boff[i] : battw[i-192];
        __syncthreads();

        // ---- MFMA: 5 feature tiles x 4 query tiles per wave ----
        const int w = t >> 6, lane = t & 63, lr = lane & 15, lg = lane >> 4;
        const int nt0 = w*5;
        f32x4 acc[5][4];
        #pragma unroll
        for (int j=0;j<5;j++)
            #pragma unroll
            for (int qt=0;qt<4;qt++) acc[j][qt] = (f32x4){0.f,0.f,0.f,0.f};

        #pragma unroll
        for (int ks=0; ks<4; ++ks){
            s16x8 bf[4];
            #pragma unroll
            for (int qt=0;qt<4;qt++){
                int qrow = qt*16 + lr;
                unsigned int bo = ((unsigned int)(qrow*256 + ks*64 + lg*16)) ^ (unsigned int)((qrow&7)<<4);
                bf[qt] = *(const s16x8*)(qbfB + bo);
            }
            const unsigned short* wp = Wbf + (size_t)(nt0*16 + lr)*CDIM + ks*32 + lg*8;
            #pragma unroll
            for (int j=0;j<5;++j){
                s16x8 af = *(const s16x8*)(wp + j*16*CDIM);
                #pragma unroll
                for (int qt=0;qt<4;qt++)
                    acc[j][qt] = __builtin_amdgcn_mfma_f32_16x16x32_bf16(af, bf[qt], acc[j][qt], 0, 0, 0);
            }
        }
        __syncthreads();   // all waves done reading qbf before Ob overwrites it

        // ---- writeback + bias into Ob[q>>3][f][q&7] ----
        #pragma unroll
        for (int j=0;j<5;++j){
            int nt = nt0 + j;
            if (nt < 18){
                #pragma unroll
                for (int qt=0;qt<4;qt++){
                    int q = qt*16 + lr;
                    int base = (q>>3)*2304 + (q&7);
                    #pragma unroll
                    for (int r=0;r<4;++r){
                        int f = nt*16 + lg*4 + r;
                        Ob[base + f*8] = f2b(acc[j][qt][r] + bias[f]);
                    }
                }
            }
        }
        __syncthreads();

        // ---- softmax over 12 logits per (query, head): 512 tasks ----
        for (int task = t; task < 512; task += 256){
            int q = task >> 3, h = task & 7;
            unsigned short* p = Ob + (q>>3)*2304 + (192 + h*12)*8 + (q&7);
            float e[12]; float m = -1e30f;
            #pragma unroll
            for (int i=0;i<12;i++){ e[i] = b2f(p[i*8]); m = fmaxf(m, e[i]); }
            float s = 0.f;
            #pragma unroll
            for (int i=0;i<12;i++){ e[i] = __expf(e[i]-m); s += e[i]; }
            float is = 1.f/s;
            #pragma unroll
            for (int i=0;i<12;i++) p[i*8] = f2b(e[i]*is);
        }
        __syncthreads();

        // ---- coalesced dump ----
        {
            const uint4* src = (const uint4*)Ob;
            uint4* dst = (uint4*)(offawB + (size_t)blockIdx.x * 18432);
            for (int idx = t; idx < 2304; idx += 256) dst[idx] = src[idx];
        }
    } else if ((int)blockIdx.x < nOff + nVal){
        // ---------- value: 8 pixels per block (two 128-thread halves) ----------
        const int half = t >> 7, tt = t & 127;
        const int p0 = (blockIdx.x - nOff)*8 + half*4;
        float (*fl)[4] = (float(*)[4])(smem + half*2048);
        const float* src; int hw, lp;
        if (p0 < 7680)      { src=f0; hw=7680; lp=p0; }
        else if (p0 < 9600) { src=f1; hw=1920; lp=p0-7680; }
        else                { src=f2; hw=480;  lp=p0-9600; }
        float4 v = *(const float4*)(src + tt*hw + lp);
        fl[tt][0]=v.x; fl[tt][1]=v.y; fl[tt][2]=v.z; fl[tt][3]=v.w;
        __syncthreads();
        float bb = bv[tt];
        float acc[4] = {bb,bb,bb,bb};
        const float4* wrow = (const float4*)(Wv + tt*CDIM);
        #pragma unroll 8
        for (int kc=0; kc<32; ++kc){
            float4 w = wrow[kc];
            #pragma unroll
            for (int u=0;u<4;u++){
                float wu = (u==0)?w.x:(u==1)?w.y:(u==2)?w.z:w.w;
                float4 fv = *(const float4*)fl[kc*4+u];
                acc[0] += fv.x*wu; acc[1] += fv.y*wu; acc[2] += fv.z*wu; acc[3] += fv.w*wu;
            }
        }
        const int hh = tt >> 4, cc = tt & 15;
        #pragma unroll
        for (int i=0;i<4;i++)
            value[((size_t)hh*NVPIX + (size_t)(p0+i))*HD + cc] = f2b(acc[i]);
    } else {
        // ---------- mask ----------
        int tid = (blockIdx.x - nOff - nVal)*256 + t;
        if (tid >= NPIX) return;
        int gx = tid % DW, gy = tid / DW;
        double d  = (double)depth[tid];
        double X0 = (double)gx * d, X1 = (double)gy * d, X2 = d;
        double c0 = invm[0]*X0 + invm[1]*X1 + invm[2]*X2;
        double c1 = invm[3]*X0 + invm[4]*X1 + invm[5]*X2;
        double c2 = invm[6]*X0 + invm[7]*X1 + invm[8]*X2;
        const double* iE = invm + 9;
        double w0 = iE[0]*c0 + iE[1]*c1 + iE[2]*c2  + iE[3];
        double w1 = iE[4]*c0 + iE[5]*c1 + iE[6]*c2  + iE[7];
        double w2 = iE[8]*c0 + iE[9]*c1 + iE[10]*c2 + iE[11];
        double v0 = (w0-(double)vorigin[0])/0.4 - 0.5;
        double v1 = (w1-(double)vorigin[1])/0.4 - 0.5;
        double v2 = ((w2-(double)vorigin[2])/0.4 - 0.5) / 2.0;
        int xi = (int)v0, yi = (int)v1, zi = (int)v2;
        if (xi>=0 && xi<XS && yi>=0 && yi<YS && zi>=0 && zi<ZS)
            mask[(xi*YS + yi)*ZS + zi] = 1;
    }
}

// ---------------- sampling + Wout(MFMA) + LN + mask + transposed store ----------------
__global__ __launch_bounds__(256, 2)
void attn_kernel(const float* __restrict__ q_in,
                 const float* __restrict__ refpix,
                 const unsigned short* __restrict__ offawB, // [len/8][288][8], chunk-local
                 const unsigned short* __restrict__ value,  // [NH][NVPIX][HD]
                 const unsigned short* __restrict__ WoutBf, // [128][128] bf16
                 const float* __restrict__ bout,
                 const float* __restrict__ lng,
                 const float* __restrict__ lnb,
                 const unsigned char* __restrict__ mask,
                 float* __restrict__ dout,
                 int q0g){
    const int n0l = blockIdx.x * 8;         // chunk-local
    const int n0g = q0g + n0l;              // global query index
    const int t = threadIdx.x;
    __shared__ __align__(16) unsigned char smem[25296];
    unsigned short* raw   = (unsigned short*)(smem);
    unsigned char*  descB = smem + 4608;
    float*          out2  = (float*)(smem + 4608);          // alias over desc
    unsigned char*  obfB  = smem + 16896;
    float (*q_s)[CDIM]    = (float(*)[CDIM])(smem + 20992);
    float*          rp_s  = (float*)(smem + 25088);
    float*          wredp = (float*)(smem + 25152);         // [2][4][4]
    unsigned char*  mask_s= (unsigned char*)(smem + 25280);

    // ---- stage ----
    {
        const unsigned int* src = (const unsigned int*)(offawB + (size_t)(n0l>>3)*2304);
        unsigned int* dst = (unsigned int*)raw;
        #pragma unroll
        for (int i=0;i<5;i++){ int idx = t + i*256; if (idx < 1152) dst[idx] = src[idx]; }
        ((float4*)q_s)[t] = ((const float4*)(q_in + (size_t)n0g*CDIM))[t];
        ((unsigned int*)obfB)[512 + t] = 0;   // zero obf rows 8..15
        ((unsigned int*)obfB)[768 + t] = 0;
        if (t < 16) rp_s[t] = refpix[n0g*2 + t];
        if (t < 8)  mask_s[t] = mask[n0g + t];
    }
    __syncthreads();

    // ---- Phase A: 768 sample descriptors ----
    for (int idx = t; idx < 768; idx += 256){
        int q = idx & 7, hp = idx >> 3;
        int lp = hp % 12;
        float fw, fh; int Wl, Hl, st;
        if (lp < 4)      { fw=160.f; fh=48.f; Wl=160; Hl=48; st=0; }
        else if (lp < 8) { fw=80.f;  fh=24.f; Wl=80;  Hl=24; st=7680; }
        else             { fw=40.f;  fh=12.f; Wl=40;  Hl=12; st=9600; }
        float offx = b2f(raw[(hp*2)*8 + q]);
        float offy = b2f(raw[(hp*2+1)*8 + q]);
        float aw   = b2f(raw[(192+hp)*8 + q]);
        float x = rp_s[q*2+0]*fw - 0.5f + offx;
        float y = rp_s[q*2+1]*fh - 0.5f + offy;
        float x0f = floorf(x), y0f = floorf(y);
        float lx = x-x0f, ly = y-y0f;
        int x0 = (int)x0f, y0 = (int)y0f;
        bool x0ok = (x0>=0)&&(x0<Wl), x1ok=(x0+1>=0)&&(x0+1<Wl);
        bool y0ok = (y0>=0)&&(y0<Hl), y1ok=(y0+1>=0)&&(y0+1<Hl);
        float w00 = (x0ok&&y0ok)? (1.f-lx)*(1.f-ly)*aw : 0.f;
        float w01 = (x1ok&&y0ok)? lx*(1.f-ly)*aw       : 0.f;
        float w10 = (x0ok&&y1ok)? (1.f-lx)*ly*aw       : 0.f;
        float w11 = (x1ok&&y1ok)? lx*ly*aw             : 0.f;
        int yc0 = min(max(y0,0),Hl-1), yc1 = min(max(y0+1,0),Hl-1);
        int xc0 = min(max(x0,0),Wl-1), xc1 = min(max(x0+1,0),Wl-1);
        unsigned int rb0 = (unsigned int)(st + yc0*Wl), rb1 = (unsigned int)(st + yc1*Wl);
        uint4 d;
        d.x = (rb0+(unsigned int)xc0) | ((rb0+(unsigned int)xc1)<<16);
        d.y = (rb1+(unsigned int)xc0) | ((rb1+(unsigned int)xc1)<<16);
        d.z = (unsigned int)f2b(w00) | ((unsigned int)f2b(w01)<<16);
        d.w = (unsigned int)f2b(w10) | ((unsigned int)f2b(w11)<<16);
        *(uint4*)(descB + (((unsigned int)(idx ^ ((idx>>5)&7)))<<4)) = d;
    }
    __syncthreads();

    // ---- sampling: 2 channels x 2 queries per thread; saddr-form u32-offset gathers ----
    {
        const int cp = t & 7, hs = (t>>3) & 7, qgs = t >> 6;
        const unsigned int vbase = (unsigned int)hs*(NVPIX*HD*2) + (unsigned int)cp*4;
        const char* vb = (const char*)value;
        float av0x=0.f, av0y=0.f, av1x=0.f, av1y=0.f;
        #pragma unroll
        for (int lp=0; lp<12; ++lp){
            #pragma unroll
            for (int qi2=0; qi2<2; ++qi2){
                int idx = (hs*12+lp)*8 + qgs*2 + qi2;
                uint4 d = *(const uint4*)(descB + (((unsigned int)(idx ^ ((idx>>5)&7)))<<4));
                unsigned int o00 = vbase + ((d.x & 0xffffu)<<5);
                unsigned int o01 = vbase + ((d.x >> 16)<<5);
                unsigned int o10 = vbase + ((d.y & 0xffffu)<<5);
                unsigned int o11 = vbase + ((d.y >> 16)<<5);
                unsigned int u00 = *(const unsigned int*)(vb + o00);
                unsigned int u01 = *(const unsigned int*)(vb + o01);
                unsigned int u10 = *(const unsigned int*)(vb + o10);
                unsigned int u11 = *(const unsigned int*)(vb + o11);
                float w00 = blo(d.z), w01 = bhi(d.z), w10 = blo(d.w), w11 = bhi(d.w);
                float sx = blo(u00)*w00 + blo(u01)*w01 + blo(u10)*w10 + blo(u11)*w11;
                float sy = bhi(u00)*w00 + bhi(u01)*w01 + bhi(u10)*w10 + bhi(u11)*w11;
                if (qi2 == 0){ av0x += sx; av0y += sy; }
                else         { av1x += sx; av1y += sy; }
            }
        }
        const int q0q = qgs*2;
        unsigned int pk0 = (unsigned int)f2b(av0x) | ((unsigned int)f2b(av0y)<<16);
        unsigned int pk1 = (unsigned int)f2b(av1x) | ((unsigned int)f2b(av1y)<<16);
        unsigned int bo0 = (unsigned int)(q0q*256 + hs*32 + cp*4)     ^ (unsigned int)((q0q&7)<<4);
        unsigned int bo1 = (unsigned int)((q0q+1)*256 + hs*32 + cp*4) ^ (unsigned int)(((q0q+1)&7)<<4);
        *(unsigned int*)(obfB + bo0) = pk0;
        *(unsigned int*)(obfB + bo1) = pk1;
    }
    __syncthreads();

    // ---- Wout projection via MFMA, bout folded ----
    {
        const int w = t >> 6, lane = t & 63, lr = lane & 15, lg = lane >> 4;
        f32x4 a0 = (f32x4){0.f,0.f,0.f,0.f};
        f32x4 a1 = (f32x4){0.f,0.f,0.f,0.f};
        #pragma unroll
        for (int ks=0; ks<4; ++ks){
            unsigned int bo = (unsigned int)(lr*256 + ks*64 + lg*16) ^ (unsigned int)((lr&7)<<4);
            s16x8 bfrag = *(const s16x8*)(obfB + bo);
            const unsigned short* wp = WoutBf + (size_t)(w*32 + lr)*CDIM + ks*32 + lg*8;
            s16x8 af0 = *(const s16x8*)(wp);
            s16x8 af1 = *(const s16x8*)(wp + 16*CDIM);
            a0 = __builtin_amdgcn_mfma_f32_16x16x32_bf16(af0, bfrag, a0, 0, 0, 0);
            a1 = __builtin_amdgcn_mfma_f32_16x16x32_bf16(af1, bfrag, a1, 0, 0, 0);
        }
        if (lr < 8){
            int f0 = w*32 + lg*4;
            float4 b0 = *(const float4*)(bout + f0);
            float4 b1 = *(const float4*)(bout + f0 + 16);
            float4 v0, v1;
            v0.x = a0[0]+b0.x; v0.y = a0[1]+b0.y; v0.z = a0[2]+b0.z; v0.w = a0[3]+b0.w;
            v1.x = a1[0]+b1.x; v1.y = a1[1]+b1.y; v1.z = a1[2]+b1.z; v1.w = a1[3]+b1.w;
            *(float4*)(out2 + lr*CDIM + f0)      = v0;
            *(float4*)(out2 + lr*CDIM + f0 + 16) = v1;
        }
    }
    __syncthreads();

    // ---- residual + single-pass LayerNorm (E[x],E[x^2]) + mask + transposed store ----
    const int r = t & 127;
    const int qb = t >> 7;
    const int wv = t >> 6;
    float acc[4];
    #pragma unroll
    for (int qi4=0;qi4<4;qi4++) acc[qi4] = out2[(qb*4+qi4)*CDIM + r];

    float hv[4], s1[4], s2[4];
    #pragma unroll
    for (int qi4=0;qi4<4;qi4++){
        hv[qi4] = q_s[qb*4+qi4][r] + acc[qi4];
        s1[qi4] = hv[qi4];
        s2[qi4] = hv[qi4]*hv[qi4];
    }
    #pragma unroll
    for (int off=32; off>0; off>>=1){
        #pragma unroll
        for (int qi4=0;qi4<4;qi4++){
            s1[qi4] += __shfl_xor(s1[qi4], off, 64);
            s2[qi4] += __shfl_xor(s2[qi4], off, 64);
        }
    }
    if ((t&63)==0){
        #pragma unroll
        for (int qi4=0;qi4<4;qi4++){
            wredp[0*16 + wv*4 + qi4] = s1[qi4];
            wredp[1*16 + wv*4 + qi4] = s2[qi4];
        }
    }
    __syncthreads();

    float res[4];
    const float g = lng[r], b = lnb[r];
    #pragma unroll
    for (int qi4=0;qi4<4;qi4++){
        float mu  = (wredp[0*16 + (qb*2)*4 + qi4] + wredp[0*16 + (qb*2+1)*4 + qi4]) * (1.f/128.f);
        float msq = (wredp[1*16 + (qb*2)*4 + qi4] + wredp[1*16 + (qb*2+1)*4 + qi4]) * (1.f/128.f);
        float var = msq - mu*mu;
        float nv  = (hv[qi4]-mu) * __frsqrt_rn(var + 1e-5f) * g + b;
        res[qi4] = mask_s[qb*4+qi4] ? nv : q_s[qb*4+qi4][r];
    }
    float4 o; o.x=res[0]; o.y=res[1]; o.z=res[2]; o.w=res[3];
    *(float4*)(dout + (size_t)r*NQ + n0g + qb*4) = o;
}

extern "C" void kernel_launch(void* const* d_in, const int* in_sizes, int n_in,
                              void* d_out, int out_size, void* d_ws, size_t ws_size,
                              hipStream_t stream){
    const float* scene  = (const float*)d_in[0];
    const float* f0     = (const float*)d_in[1];
    const float* f1     = (const float*)d_in[2];
    const float* f2     = (const float*)d_in[3];
    const float* depth  = (const float*)d_in[4];
    const float* K      = (const float*)d_in[5];
    const float* E      = (const float*)d_in[6];
    const float* vorig  = (const float*)d_in[7];
    const float* refpix = (const float*)d_in[8];
    const float* Wv     = (const float*)d_in[9];
    const float* bv     = (const float*)d_in[10];
    const float* Woff   = (const float*)d_in[11];
    const float* boff   = (const float*)d_in[12];
    const float* Wattw  = (const float*)d_in[13];
    const float* battw  = (const float*)d_in[14];
    const float* Wout   = (const float*)d_in[15];
    const float* bout   = (const float*)d_in[16];
    const float* lng    = (const float*)d_in[17];
    const float* lnb    = (const float*)d_in[18];

    char* ws = (char*)d_ws;
    // invm(512) + mask(131072) + value(2580480) + Wbf(114688) + offawB(rest)
    const size_t FIXED = 512 + 131072 + 2580480 + 114688;
    double*         invm   = (double*)(ws);
    unsigned char*  mask   = (unsigned char*)(ws + 512);
    unsigned short* value  = (unsigned short*)(ws + 512 + 131072);
    unsigned short* Wbf    = (unsigned short*)(ws + 512 + 131072 + 2580480);
    unsigned short* WoutBf = Wbf + 40960;
    unsigned short* offawB = (unsigned short*)(ws + FIXED);

    size_t avail = (ws_size > FIXED) ? (ws_size - FIXED) : 0;
    long long maxq = (long long)(avail / (288*2));
    int chunk = (int)((maxq/64)*64);
    if (chunk > NQ) chunk = NQ;
    if (chunk < 64) chunk = 64;

    hipMemsetAsync(mask, 0, NQ, stream);
    inv_kernel<<<225, 256, 0, stream>>>(K, E, invm, Woff, Wattw, Wout, Wbf);

    for (int q0 = 0; q0 < NQ; q0 += chunk){
        int len = (NQ - q0 < chunk) ? (NQ - q0) : chunk;
        int nOff  = len/64;
        int nVal  = (q0 == 0) ? (NVPIX/8) : 0;          // 1260
        int nMask = (q0 == 0) ? ((NPIX+255)/256) : 0;   // 480
        prep_kernel<<<nOff + nVal + nMask, 256, 0, stream>>>(
            scene + (size_t)q0*CDIM, Wbf, boff, battw, offawB,
            nOff, nVal,
            f0, f1, f2, Wv, bv, value,
            depth, invm, vorig, mask);
        attn_kernel<<<len/8, 256, 0, stream>>>(scene, refpix, offawB, value,
                                               WoutBf, bout, lng, lnb, mask,
                                               (float*)d_out, q0);
    }
}

// Round 10
// 401.766 us; speedup vs baseline: 1.0553x; 1.0517x over previous
//
#include <hip/hip_runtime.h>
#include <hip/hip_bf16.h>
#include <stdint.h>

#define XS 128
#define YS 128
#define ZS 8
#define NQ (XS*YS*ZS)        // 131072 queries
#define CDIM 128
#define NH 8
#define HD 16
#define DH 192
#define DW 640
#define NPIX (DH*DW)
#define NVPIX 10080          // 7680 + 1920 + 480

typedef float f32x4 __attribute__((ext_vector_type(4)));
typedef short s16x8 __attribute__((ext_vector_type(8)));

__device__ __forceinline__ float b2f(unsigned short u){
    union { unsigned int i; float f; } v; v.i = ((unsigned int)u) << 16; return v.f;
}
__device__ __forceinline__ unsigned short f2b(float f){
    __hip_bfloat16 h = __float2bfloat16(f);
    return *reinterpret_cast<unsigned short*>(&h);
}
__device__ __forceinline__ float blo(unsigned int u){
    union { unsigned int i; float f; } v; v.i = u << 16; return v.f;
}
__device__ __forceinline__ float bhi(unsigned int u){
    union { unsigned int i; float f; } v; v.i = u & 0xffff0000u; return v.f;
}

// ------------- inverse of K/E (1 thread) + Woff/Wattw/Wout -> bf16 (padded) -------------
// Wbf layout: [0,24576) Woff | [24576,36864) Wattw | [36864,40960) zero pad (tiles 18,19)
//             [40960,57344) Wout
__global__ __launch_bounds__(256)
void inv_kernel(const float* __restrict__ K,
                const float* __restrict__ E,
                double* __restrict__ inv_out,
                const float* __restrict__ Woff,
                const float* __restrict__ Wattw,
                const float* __restrict__ Wout,
                unsigned short* __restrict__ Wbf){
    if (blockIdx.x != 0){
        int idx = (blockIdx.x-1)*256 + threadIdx.x;
        if (idx < 24576)      Wbf[idx] = f2b(Woff[idx]);
        else if (idx < 36864) Wbf[idx] = f2b(Wattw[idx-24576]);
        else if (idx < 40960) Wbf[idx] = 0;
        else if (idx < 57344) Wbf[idx] = f2b(Wout[idx-40960]);
        return;
    }
    if (threadIdx.x != 0) return;
    double k[3][3], e[4][4];
    for (int i=0;i<9;i++)  k[i/3][i%3] = (double)K[i];
    for (int i=0;i<16;i++) e[i/4][i%4] = (double)E[i];
    double det = k[0][0]*(k[1][1]*k[2][2]-k[1][2]*k[2][1])
               - k[0][1]*(k[1][0]*k[2][2]-k[1][2]*k[2][0])
               + k[0][2]*(k[1][0]*k[2][1]-k[1][1]*k[2][0]);
    double id = 1.0/det;
    double inv[3][3];
    inv[0][0]=(k[1][1]*k[2][2]-k[1][2]*k[2][1])*id;
    inv[0][1]=(k[0][2]*k[2][1]-k[0][1]*k[2][2])*id;
    inv[0][2]=(k[0][1]*k[1][2]-k[0][2]*k[1][1])*id;
    inv[1][0]=(k[1][2]*k[2][0]-k[1][0]*k[2][2])*id;
    inv[1][1]=(k[0][0]*k[2][2]-k[0][2]*k[2][0])*id;
    inv[1][2]=(k[0][2]*k[1][0]-k[0][0]*k[1][2])*id;
    inv[2][0]=(k[1][0]*k[2][1]-k[1][1]*k[2][0])*id;
    inv[2][1]=(k[0][1]*k[2][0]-k[0][0]*k[2][1])*id;
    inv[2][2]=(k[0][0]*k[1][1]-k[0][1]*k[1][0])*id;
    for (int i=0;i<9;i++) inv_out[i] = inv[i/3][i%3];
    double a[4][8];
    for (int i=0;i<4;i++){ for(int j=0;j<4;j++){ a[i][j]=e[i][j]; a[i][4+j]=(i==j)?1.0:0.0; } }
    for (int c=0;c<4;c++){
        int piv=c; double best=fabs(a[c][c]);
        for (int r=c+1;r<4;r++){ double v=fabs(a[r][c]); if (v>best){best=v;piv=r;} }
        if (piv!=c){ for (int j=0;j<8;j++){ double tmp=a[c][j]; a[c][j]=a[piv][j]; a[piv][j]=tmp; } }
        double pv = 1.0/a[c][c];
        for (int j=0;j<8;j++) a[c][j]*=pv;
        for (int r=0;r<4;r++){
            if (r==c) continue;
            double f=a[r][c];
            for(int j=0;j<8;j++) a[r][j]-=f*a[c][j];
        }
    }
    for (int i=0;i<16;i++) inv_out[9+i] = a[i/4][4 + (i%4)];
}

// ================= prep2: value GEMM | mask (independent of queries) =================
__global__ __launch_bounds__(256)
void prep2_kernel(int nVal,
                  const float* __restrict__ f0,
                  const float* __restrict__ f1,
                  const float* __restrict__ f2,
                  const float* __restrict__ Wv,
                  const float* __restrict__ bv,
                  unsigned short* __restrict__ value,  // [NH][NVPIX][HD]
                  const float* __restrict__ depth,
                  const double* __restrict__ invm,
                  const float* __restrict__ vorigin,
                  unsigned char* __restrict__ mask){
    __shared__ float fl2[2][CDIM][4];
    const int t = threadIdx.x;
    if ((int)blockIdx.x < nVal){
        const int half = t >> 7, tt = t & 127;
        const int p0 = blockIdx.x*8 + half*4;
        float (*fl)[4] = fl2[half];
        const float* src; int hw, lp;
        if (p0 < 7680)      { src=f0; hw=7680; lp=p0; }
        else if (p0 < 9600) { src=f1; hw=1920; lp=p0-7680; }
        else                { src=f2; hw=480;  lp=p0-9600; }
        float4 v = *(const float4*)(src + tt*hw + lp);
        fl[tt][0]=v.x; fl[tt][1]=v.y; fl[tt][2]=v.z; fl[tt][3]=v.w;
        __syncthreads();
        float bb = bv[tt];
        float acc[4] = {bb,bb,bb,bb};
        const float4* wrow = (const float4*)(Wv + tt*CDIM);
        #pragma unroll 8
        for (int kc=0; kc<32; ++kc){
            float4 w = wrow[kc];
            #pragma unroll
            for (int u=0;u<4;u++){
                float wu = (u==0)?w.x:(u==1)?w.y:(u==2)?w.z:w.w;
                float4 fv = *(const float4*)fl[kc*4+u];
                acc[0] += fv.x*wu; acc[1] += fv.y*wu; acc[2] += fv.z*wu; acc[3] += fv.w*wu;
            }
        }
        const int hh = tt >> 4, cc = tt & 15;
        #pragma unroll
        for (int i=0;i<4;i++)
            value[((size_t)hh*NVPIX + (size_t)(p0+i))*HD + cc] = f2b(acc[i]);
    } else {
        int tid = (blockIdx.x - nVal)*256 + t;
        if (tid >= NPIX) return;
        int gx = tid % DW, gy = tid / DW;
        double d  = (double)depth[tid];
        double X0 = (double)gx * d, X1 = (double)gy * d, X2 = d;
        double c0 = invm[0]*X0 + invm[1]*X1 + invm[2]*X2;
        double c1 = invm[3]*X0 + invm[4]*X1 + invm[5]*X2;
        double c2 = invm[6]*X0 + invm[7]*X1 + invm[8]*X2;
        const double* iE = invm + 9;
        double w0 = iE[0]*c0 + iE[1]*c1 + iE[2]*c2  + iE[3];
        double w1 = iE[4]*c0 + iE[5]*c1 + iE[6]*c2  + iE[7];
        double w2 = iE[8]*c0 + iE[9]*c1 + iE[10]*c2 + iE[11];
        double v0 = (w0-(double)vorigin[0])/0.4 - 0.5;
        double v1 = (w1-(double)vorigin[1])/0.4 - 0.5;
        double v2 = ((w2-(double)vorigin[2])/0.4 - 0.5) / 2.0;
        int xi = (int)v0, yi = (int)v1, zi = (int)v2;
        if (xi>=0 && xi<XS && yi>=0 && yi<YS && zi>=0 && zi<ZS)
            mask[(xi*YS + yi)*ZS + zi] = 1;
    }
}

// ======== attn_fused32: offaw MFMA + softmax + 4x{desc, sampling, Wout MFMA, LN} ========
// 32 queries/block. LDS map (36384 B total):
//   0      Ob[4][288][8] u16 logits/weights       (18432)
//   18432  regC: qbf[32][128]bf16 swz (8192, ph0-1) / desc[768]x16B (12288, per sub-round)
//                 / out2[8][128] f32 (4096, per sub-round)   -- all barrier-separated
//   30720  obf[16][128] bf16 swz                  (4096)
//   34816  bias[288] f32                          (1152)
//   35968  rp_s[64] f32                           (256)
//   36224  mask_s[32]                             (32)
//   36256  wredp[2][4][4] f32                     (128)
__global__ __launch_bounds__(256, 2)
void attn_fused(const float* __restrict__ q_in,
                const float* __restrict__ refpix,
                const unsigned short* __restrict__ Wbf,    // [320][128] bf16 (padded)
                const float* __restrict__ boff,
                const float* __restrict__ battw,
                const unsigned short* __restrict__ value,  // [NH][NVPIX][HD]
                const unsigned short* __restrict__ WoutBf, // [128][128] bf16
                const float* __restrict__ bout,
                const float* __restrict__ lng,
                const float* __restrict__ lnb,
                const unsigned char* __restrict__ mask,
                float* __restrict__ dout){
    const int nq0 = blockIdx.x * 32;
    const int t = threadIdx.x;
    __shared__ __align__(16) unsigned char smem[36384];
    unsigned short* Ob    = (unsigned short*)smem;
    unsigned char*  qbfB  = smem + 18432;
    unsigned char*  descB = smem + 18432;
    float*          out2  = (float*)(smem + 18432);
    unsigned char*  obfB  = smem + 30720;
    float*          bias  = (float*)(smem + 34816);
    float*          rp_s  = (float*)(smem + 35968);
    unsigned char*  mask_s= smem + 36224;
    float*          wredp = (float*)(smem + 36256);

    // ---- stage: q -> swizzled bf16, bias, rp, mask, zero obf pad rows ----
    #pragma unroll
    for (int i=0;i<4;i++){
        int idx = t + i*256;              // 1024 float4s = 32 rows x 32
        int row = idx >> 5, c4 = idx & 31;
        float4 qv = ((const float4*)(q_in + (size_t)(nq0+row)*CDIM))[c4];
        unsigned int pk0 = (unsigned int)f2b(qv.x) | ((unsigned int)f2b(qv.y)<<16);
        unsigned int pk1 = (unsigned int)f2b(qv.z) | ((unsigned int)f2b(qv.w)<<16);
        unsigned int bo = ((unsigned int)(row*256 + c4*8)) ^ (unsigned int)((row&7)<<4);
        *(unsigned int*)(qbfB + bo)     = pk0;
        *(unsigned int*)(qbfB + bo + 4) = pk1;
    }
    for (int i=t;i<288;i+=256) bias[i] = (i<192)? boff[i] : battw[i-192];
    ((unsigned int*)obfB)[512 + t] = 0;   // zero obf rows 8..15
    ((unsigned int*)obfB)[768 + t] = 0;
    if (t < 64) rp_s[t] = refpix[nq0*2 + t];
    if (t < 32) mask_s[t] = mask[nq0 + t];
    __syncthreads();

    // ---- offaw MFMA: 5 feature tiles x 2 query tiles x 4 K-steps per wave ----
    {
        const int w = t >> 6, lane = t & 63, lr = lane & 15, lg = lane >> 4;
        const int nt0 = w*5;
        f32x4 acc[5][2];
        #pragma unroll
        for (int j=0;j<5;j++){ acc[j][0]=(f32x4){0,0,0,0}; acc[j][1]=(f32x4){0,0,0,0}; }
        #pragma unroll
        for (int ks=0; ks<4; ++ks){
            s16x8 bf[2];
            #pragma unroll
            for (int qt=0;qt<2;qt++){
                int qrow = qt*16 + lr;
                unsigned int bo = ((unsigned int)(qrow*256 + ks*64 + lg*16)) ^ (unsigned int)((qrow&7)<<4);
                bf[qt] = *(const s16x8*)(qbfB + bo);
            }
            const unsigned short* wp = Wbf + (size_t)(nt0*16 + lr)*CDIM + ks*32 + lg*8;
            #pragma unroll
            for (int j=0;j<5;++j){
                s16x8 af = *(const s16x8*)(wp + j*16*CDIM);
                acc[j][0] = __builtin_amdgcn_mfma_f32_16x16x32_bf16(af, bf[0], acc[j][0], 0, 0, 0);
                acc[j][1] = __builtin_amdgcn_mfma_f32_16x16x32_bf16(af, bf[1], acc[j][1], 0, 0, 0);
            }
        }
        // writeback + bias (all 16 cols are real queries)
        #pragma unroll
        for (int j=0;j<5;++j){
            int nt = nt0 + j;
            if (nt < 18){
                #pragma unroll
                for (int qt=0;qt<2;qt++){
                    int q = qt*16 + lr;
                    int base = (q>>3)*2304 + (q&7);
                    #pragma unroll
                    for (int r=0;r<4;++r){
                        int f = nt*16 + lg*4 + r;
                        Ob[base + f*8] = f2b(acc[j][qt][r] + bias[f]);
                    }
                }
            }
        }
    }
    __syncthreads();

    // ---- softmax: 32q x 8h = 256 tasks, one per thread ----
    {
        int q = t >> 3, h = t & 7;
        unsigned short* p = Ob + (q>>3)*2304 + (192 + h*12)*8 + (q&7);
        float e[12]; float m = -1e30f;
        #pragma unroll
        for (int i=0;i<12;i++){ e[i] = b2f(p[i*8]); m = fmaxf(m, e[i]); }
        float s = 0.f;
        #pragma unroll
        for (int i=0;i<12;i++){ e[i] = __expf(e[i]-m); s += e[i]; }
        float is = 1.f/s;
        #pragma unroll
        for (int i=0;i<12;i++) p[i*8] = f2b(e[i]*is);
    }
    __syncthreads();

    // ---- 4 sub-rounds of 8 queries ----
    for (int sr = 0; sr < 4; ++sr){
        const unsigned short* raw = Ob + sr*2304;
        const int nsr = nq0 + sr*8;

        // desc: 768 sample descriptors
        for (int idx = t; idx < 768; idx += 256){
            int q = idx & 7, hp = idx >> 3;
            int lp = hp % 12;
            float fw, fh; int Wl, Hl, st;
            if (lp < 4)      { fw=160.f; fh=48.f; Wl=160; Hl=48; st=0; }
            else if (lp < 8) { fw=80.f;  fh=24.f; Wl=80;  Hl=24; st=7680; }
            else             { fw=40.f;  fh=12.f; Wl=40;  Hl=12; st=9600; }
            float offx = b2f(raw[(hp*2)*8 + q]);
            float offy = b2f(raw[(hp*2+1)*8 + q]);
            float aw   = b2f(raw[(192+hp)*8 + q]);
            float x = rp_s[(sr*8+q)*2+0]*fw - 0.5f + offx;
            float y = rp_s[(sr*8+q)*2+1]*fh - 0.5f + offy;
            float x0f = floorf(x), y0f = floorf(y);
            float lx = x-x0f, ly = y-y0f;
            int x0 = (int)x0f, y0 = (int)y0f;
            bool x0ok = (x0>=0)&&(x0<Wl), x1ok=(x0+1>=0)&&(x0+1<Wl);
            bool y0ok = (y0>=0)&&(y0<Hl), y1ok=(y0+1>=0)&&(y0+1<Hl);
            float w00 = (x0ok&&y0ok)? (1.f-lx)*(1.f-ly)*aw : 0.f;
            float w01 = (x1ok&&y0ok)? lx*(1.f-ly)*aw       : 0.f;
            float w10 = (x0ok&&y1ok)? (1.f-lx)*ly*aw       : 0.f;
            float w11 = (x1ok&&y1ok)? lx*ly*aw             : 0.f;
            int yc0 = min(max(y0,0),Hl-1), yc1 = min(max(y0+1,0),Hl-1);
            int xc0 = min(max(x0,0),Wl-1), xc1 = min(max(x0+1,0),Wl-1);
            unsigned int rb0 = (unsigned int)(st + yc0*Wl), rb1 = (unsigned int)(st + yc1*Wl);
            uint4 d;
            d.x = (rb0+(unsigned int)xc0) | ((rb0+(unsigned int)xc1)<<16);
            d.y = (rb1+(unsigned int)xc0) | ((rb1+(unsigned int)xc1)<<16);
            d.z = (unsigned int)f2b(w00) | ((unsigned int)f2b(w01)<<16);
            d.w = (unsigned int)f2b(w10) | ((unsigned int)f2b(w11)<<16);
            *(uint4*)(descB + (((unsigned int)(idx ^ ((idx>>5)&7)))<<4)) = d;
        }
        __syncthreads();

        // sampling: 2 channels x 2 queries per thread, u32-offset gathers
        {
            const int cp = t & 7, hs = (t>>3) & 7, qgs = t >> 6;
            const unsigned int vbase = (unsigned int)hs*(NVPIX*HD*2) + (unsigned int)cp*4;
            const char* vb = (const char*)value;
            float av0x=0.f, av0y=0.f, av1x=0.f, av1y=0.f;
            #pragma unroll
            for (int lp=0; lp<12; ++lp){
                #pragma unroll
                for (int qi2=0; qi2<2; ++qi2){
                    int idx = (hs*12+lp)*8 + qgs*2 + qi2;
                    uint4 d = *(const uint4*)(descB + (((unsigned int)(idx ^ ((idx>>5)&7)))<<4));
                    unsigned int o00 = vbase + ((d.x & 0xffffu)<<5);
                    unsigned int o01 = vbase + ((d.x >> 16)<<5);
                    unsigned int o10 = vbase + ((d.y & 0xffffu)<<5);
                    unsigned int o11 = vbase + ((d.y >> 16)<<5);
                    unsigned int u00 = *(const unsigned int*)(vb + o00);
                    unsigned int u01 = *(const unsigned int*)(vb + o01);
                    unsigned int u10 = *(const unsigned int*)(vb + o10);
                    unsigned int u11 = *(const unsigned int*)(vb + o11);
                    float w00 = blo(d.z), w01 = bhi(d.z), w10 = blo(d.w), w11 = bhi(d.w);
                    float sx = blo(u00)*w00 + blo(u01)*w01 + blo(u10)*w10 + blo(u11)*w11;
                    float sy = bhi(u00)*w00 + bhi(u01)*w01 + bhi(u10)*w10 + bhi(u11)*w11;
                    if (qi2 == 0){ av0x += sx; av0y += sy; }
                    else         { av1x += sx; av1y += sy; }
                }
            }
            const int q0q = qgs*2;
            unsigned int pk0 = (unsigned int)f2b(av0x) | ((unsigned int)f2b(av0y)<<16);
            unsigned int pk1 = (unsigned int)f2b(av1x) | ((unsigned int)f2b(av1y)<<16);
            unsigned int bo0 = (unsigned int)(q0q*256 + hs*32 + cp*4)     ^ (unsigned int)((q0q&7)<<4);
            unsigned int bo1 = (unsigned int)((q0q+1)*256 + hs*32 + cp*4) ^ (unsigned int)(((q0q+1)&7)<<4);
            *(unsigned int*)(obfB + bo0) = pk0;
            *(unsigned int*)(obfB + bo1) = pk1;
        }
        __syncthreads();

        // Wout projection via MFMA, bout folded
        {
            const int w = t >> 6, lane = t & 63, lr = lane & 15, lg = lane >> 4;
            f32x4 a0 = (f32x4){0.f,0.f,0.f,0.f};
            f32x4 a1 = (f32x4){0.f,0.f,0.f,0.f};
            #pragma unroll
            for (int ks=0; ks<4; ++ks){
                unsigned int bo = (unsigned int)(lr*256 + ks*64 + lg*16) ^ (unsigned int)((lr&7)<<4);
                s16x8 bfrag = *(const s16x8*)(obfB + bo);
                const unsigned short* wp = WoutBf + (size_t)(w*32 + lr)*CDIM + ks*32 + lg*8;
                s16x8 af0 = *(const s16x8*)(wp);
                s16x8 af1 = *(const s16x8*)(wp + 16*CDIM);
                a0 = __builtin_amdgcn_mfma_f32_16x16x32_bf16(af0, bfrag, a0, 0, 0, 0);
                a1 = __builtin_amdgcn_mfma_f32_16x16x32_bf16(af1, bfrag, a1, 0, 0, 0);
            }
            if (lr < 8){
                int f0 = w*32 + lg*4;
                float4 b0 = *(const float4*)(bout + f0);
                float4 b1 = *(const float4*)(bout + f0 + 16);
                float4 v0, v1;
                v0.x = a0[0]+b0.x; v0.y = a0[1]+b0.y; v0.z = a0[2]+b0.z; v0.w = a0[3]+b0.w;
                v1.x = a1[0]+b1.x; v1.y = a1[1]+b1.y; v1.z = a1[2]+b1.z; v1.w = a1[3]+b1.w;
                *(float4*)(out2 + lr*CDIM + f0)      = v0;
                *(float4*)(out2 + lr*CDIM + f0 + 16) = v1;
            }
        }
        __syncthreads();

        // residual (q re-read from global, L2-hot) + single-pass LN + mask + store
        {
            const int r = t & 127;
            const int qb = t >> 7;
            const int wv = t >> 6;
            float qv[4], hv[4], s1[4], s2[4];
            #pragma unroll
            for (int qi4=0;qi4<4;qi4++){
                qv[qi4] = q_in[(size_t)(nsr + qb*4 + qi4)*CDIM + r];
                hv[qi4] = qv[qi4] + out2[(qb*4+qi4)*CDIM + r];
                s1[qi4] = hv[qi4];
                s2[qi4] = hv[qi4]*hv[qi4];
            }
            #pragma unroll
            for (int off=32; off>0; off>>=1){
                #pragma unroll
                for (int qi4=0;qi4<4;qi4++){
                    s1[qi4] += __shfl_xor(s1[qi4], off, 64);
                    s2[qi4] += __shfl_xor(s2[qi4], off, 64);
                }
            }
            if ((t&63)==0){
                #pragma unroll
                for (int qi4=0;qi4<4;qi4++){
                    wredp[0*16 + wv*4 + qi4] = s1[qi4];
                    wredp[1*16 + wv*4 + qi4] = s2[qi4];
                }
            }
            __syncthreads();

            float res[4];
            const float g = lng[r], b = lnb[r];
            #pragma unroll
            for (int qi4=0;qi4<4;qi4++){
                float mu  = (wredp[0*16 + (qb*2)*4 + qi4] + wredp[0*16 + (qb*2+1)*4 + qi4]) * (1.f/128.f);
                float msq = (wredp[1*16 + (qb*2)*4 + qi4] + wredp[1*16 + (qb*2+1)*4 + qi4]) * (1.f/128.f);
                float var = msq - mu*mu;
                float nv  = (hv[qi4]-mu) * __frsqrt_rn(var + 1e-5f) * g + b;
                res[qi4] = mask_s[sr*8 + qb*4+qi4] ? nv : qv[qi4];
            }
            float4 o; o.x=res[0]; o.y=res[1]; o.z=res[2]; o.w=res[3];
            *(float4*)(dout + (size_t)r*NQ + nsr + qb*4) = o;
        }
        __syncthreads();   // out2/desc region + wredp safe for next sub-round
    }
}

extern "C" void kernel_launch(void* const* d_in, const int* in_sizes, int n_in,
                              void* d_out, int out_size, void* d_ws, size_t ws_size,
                              hipStream_t stream){
    const float* scene  = (const float*)d_in[0];
    const float* f0     = (const float*)d_in[1];
    const float* f1     = (const float*)d_in[2];
    const float* f2     = (const float*)d_in[3];
    const float* depth  = (const float*)d_in[4];
    const float* K      = (const float*)d_in[5];
    const float* E      = (const float*)d_in[6];
    const float* vorig  = (const float*)d_in[7];
    const float* refpix = (const float*)d_in[8];
    const float* Wv     = (const float*)d_in[9];
    const float* bv     = (const float*)d_in[10];
    const float* Woff   = (const float*)d_in[11];
    const float* boff   = (const float*)d_in[12];
    const float* Wattw  = (const float*)d_in[13];
    const float* battw  = (const float*)d_in[14];
    const float* Wout   = (const float*)d_in[15];
    const float* bout   = (const float*)d_in[16];
    const float* lng    = (const float*)d_in[17];
    const float* lnb    = (const float*)d_in[18];

    char* ws = (char*)d_ws;
    // invm(512) + mask(131072) + value(2580480) + Wbf(114688). No offawB needed.
    double*         invm   = (double*)(ws);
    unsigned char*  mask   = (unsigned char*)(ws + 512);
    unsigned short* value  = (unsigned short*)(ws + 512 + 131072);
    unsigned short* Wbf    = (unsigned short*)(ws + 512 + 131072 + 2580480);
    unsigned short* WoutBf = Wbf + 40960;

    hipMemsetAsync(mask, 0, NQ, stream);
    inv_kernel<<<225, 256, 0, stream>>>(K, E, invm, Woff, Wattw, Wout, Wbf);

    int nVal  = NVPIX/8;            // 1260
    int nMask = (NPIX+255)/256;     // 480
    prep2_kernel<<<nVal + nMask, 256, 0, stream>>>(nVal, f0, f1, f2, Wv, bv, value,
                                                   depth, invm, vorig, mask);
    attn_fused<<<NQ/32, 256, 0, stream>>>(scene, refpix, Wbf, boff, battw, value,
                                          WoutBf, bout, lng, lnb, mask,
                                          (float*)d_out);
}

// Round 11
// 395.728 us; speedup vs baseline: 1.0714x; 1.0153x over previous
//
#include <hip/hip_runtime.h>
#include <hip/hip_bf16.h>
#include <stdint.h>

#define XS 128
#define YS 128
#define ZS 8
#define NQ (XS*YS*ZS)        // 131072 queries
#define CDIM 128
#define NH 8
#define HD 16
#define DH 192
#define DW 640
#define NPIX (DH*DW)
#define NVPIX 10080          // 7680 + 1920 + 480

typedef float f32x4 __attribute__((ext_vector_type(4)));
typedef short s16x8 __attribute__((ext_vector_type(8)));

__device__ __forceinline__ float b2f(unsigned short u){
    union { unsigned int i; float f; } v; v.i = ((unsigned int)u) << 16; return v.f;
}
__device__ __forceinline__ unsigned short f2b(float f){
    __hip_bfloat16 h = __float2bfloat16(f);
    return *reinterpret_cast<unsigned short*>(&h);
}
__device__ __forceinline__ float blo(unsigned int u){
    union { unsigned int i; float f; } v; v.i = u << 16; return v.f;
}
__device__ __forceinline__ float bhi(unsigned int u){
    union { unsigned int i; float f; } v; v.i = u & 0xffff0000u; return v.f;
}

// ------------- inverse of K/E (1 thread) + weight prep -------------
// Wbf: [0,24576) Woff | [24576,36864) Wattw | [36864,40960) zero pad | [40960,57344) Wout
// WvT (f32): WvT[ci*128+co] = Wv[co*128+ci]  (coalesced value-GEMM weights)
__global__ __launch_bounds__(256)
void inv_kernel(const float* __restrict__ K,
                const float* __restrict__ E,
                double* __restrict__ inv_out,
                const float* __restrict__ Woff,
                const float* __restrict__ Wattw,
                const float* __restrict__ Wout,
                const float* __restrict__ Wv,
                unsigned short* __restrict__ Wbf,
                float* __restrict__ WvT){
    if (blockIdx.x != 0){
        int idx = (blockIdx.x-1)*256 + threadIdx.x;
        if (idx < 24576)      Wbf[idx] = f2b(Woff[idx]);
        else if (idx < 36864) Wbf[idx] = f2b(Wattw[idx-24576]);
        else if (idx < 40960) Wbf[idx] = 0;
        else if (idx < 57344) Wbf[idx] = f2b(Wout[idx-40960]);
        else if (idx < 73728){
            int j = idx - 57344;
            int ci = j >> 7, co = j & 127;
            WvT[j] = Wv[co*128 + ci];
        }
        return;
    }
    if (threadIdx.x != 0) return;
    double k[3][3], e[4][4];
    for (int i=0;i<9;i++)  k[i/3][i%3] = (double)K[i];
    for (int i=0;i<16;i++) e[i/4][i%4] = (double)E[i];
    double det = k[0][0]*(k[1][1]*k[2][2]-k[1][2]*k[2][1])
               - k[0][1]*(k[1][0]*k[2][2]-k[1][2]*k[2][0])
               + k[0][2]*(k[1][0]*k[2][1]-k[1][1]*k[2][0]);
    double id = 1.0/det;
    double inv[3][3];
    inv[0][0]=(k[1][1]*k[2][2]-k[1][2]*k[2][1])*id;
    inv[0][1]=(k[0][2]*k[2][1]-k[0][1]*k[2][2])*id;
    inv[0][2]=(k[0][1]*k[1][2]-k[0][2]*k[1][1])*id;
    inv[1][0]=(k[1][2]*k[2][0]-k[1][0]*k[2][2])*id;
    inv[1][1]=(k[0][0]*k[2][2]-k[0][2]*k[2][0])*id;
    inv[1][2]=(k[0][2]*k[1][0]-k[0][0]*k[1][2])*id;
    inv[2][0]=(k[1][0]*k[2][1]-k[1][1]*k[2][0])*id;
    inv[2][1]=(k[0][1]*k[2][0]-k[0][0]*k[2][1])*id;
    inv[2][2]=(k[0][0]*k[1][1]-k[0][1]*k[1][0])*id;
    for (int i=0;i<9;i++) inv_out[i] = inv[i/3][i%3];
    double a[4][8];
    for (int i=0;i<4;i++){ for(int j=0;j<4;j++){ a[i][j]=e[i][j]; a[i][4+j]=(i==j)?1.0:0.0; } }
    for (int c=0;c<4;c++){
        int piv=c; double best=fabs(a[c][c]);
        for (int r=c+1;r<4;r++){ double v=fabs(a[r][c]); if (v>best){best=v;piv=r;} }
        if (piv!=c){ for (int j=0;j<8;j++){ double tmp=a[c][j]; a[c][j]=a[piv][j]; a[piv][j]=tmp; } }
        double pv = 1.0/a[c][c];
        for (int j=0;j<8;j++) a[c][j]*=pv;
        for (int r=0;r<4;r++){
            if (r==c) continue;
            double f=a[r][c];
            for(int j=0;j<8;j++) a[r][j]-=f*a[c][j];
        }
    }
    for (int i=0;i<16;i++) inv_out[9+i] = a[i/4][4 + (i%4)];
}

// ================= prep2: value GEMM (WvT-coalesced) | mask =================
__global__ __launch_bounds__(256)
void prep2_kernel(int nVal,
                  const float* __restrict__ f0,
                  const float* __restrict__ f1,
                  const float* __restrict__ f2,
                  const float* __restrict__ WvT,   // [128 ci][128 co] f32
                  const float* __restrict__ bv,
                  unsigned short* __restrict__ value,  // [NH][NVPIX][HD]
                  const float* __restrict__ depth,
                  const double* __restrict__ invm,
                  const float* __restrict__ vorigin,
                  unsigned char* __restrict__ mask){
    __shared__ float fl[128][8];     // [ci][pix]
    const int t = threadIdx.x;
    if ((int)blockIdx.x < nVal){
        // ---------- value: 8 pixels/block; thread = (pix, co-quad) ----------
        const int p0 = blockIdx.x*8;
        const float* src; int hw, lp;
        if (p0 < 7680)      { src=f0; hw=7680; lp=p0; }
        else if (p0 < 9600) { src=f1; hw=1920; lp=p0-7680; }
        else                { src=f2; hw=480;  lp=p0-9600; }
        // stage: thread t loads float4 of channel t>>1, pixels (t&1)*4..+3
        {
            int ch = t >> 1, po = (t & 1)*4;
            float4 v = *(const float4*)(src + (size_t)ch*hw + lp + po);
            fl[ch][po+0]=v.x; fl[ch][po+1]=v.y; fl[ch][po+2]=v.z; fl[ch][po+3]=v.w;
        }
        __syncthreads();
        const int pix = t >> 5, cq = t & 31;      // co = cq*4 .. cq*4+3
        float4 bvv = *(const float4*)(bv + cq*4);
        float acc0=bvv.x, acc1=bvv.y, acc2=bvv.z, acc3=bvv.w;
        const float4* wvt = (const float4*)WvT + cq;   // row ci: wvt[ci*32]
        #pragma unroll 4
        for (int ci=0; ci<128; ++ci){
            float4 w4 = wvt[ci*32];               // coalesced 512B/wave
            float fv = fl[ci][pix];               // broadcast
            acc0 += w4.x*fv; acc1 += w4.y*fv; acc2 += w4.z*fv; acc3 += w4.w*fv;
        }
        const int h = cq >> 2, cc0 = (cq & 3)*4;
        unsigned short* vp = value + ((size_t)h*NVPIX + (size_t)(p0+pix))*HD + cc0;
        ushort4 o; o.x=f2b(acc0); o.y=f2b(acc1); o.z=f2b(acc2); o.w=f2b(acc3);
        *(ushort4*)vp = o;
    } else {
        int tid = (blockIdx.x - nVal)*256 + t;
        if (tid >= NPIX) return;
        int gx = tid % DW, gy = tid / DW;
        double d  = (double)depth[tid];
        double X0 = (double)gx * d, X1 = (double)gy * d, X2 = d;
        double c0 = invm[0]*X0 + invm[1]*X1 + invm[2]*X2;
        double c1 = invm[3]*X0 + invm[4]*X1 + invm[5]*X2;
        double c2 = invm[6]*X0 + invm[7]*X1 + invm[8]*X2;
        const double* iE = invm + 9;
        double w0 = iE[0]*c0 + iE[1]*c1 + iE[2]*c2  + iE[3];
        double w1 = iE[4]*c0 + iE[5]*c1 + iE[6]*c2  + iE[7];
        double w2 = iE[8]*c0 + iE[9]*c1 + iE[10]*c2 + iE[11];
        double v0 = (w0-(double)vorigin[0])/0.4 - 0.5;
        double v1 = (w1-(double)vorigin[1])/0.4 - 0.5;
        double v2 = ((w2-(double)vorigin[2])/0.4 - 0.5) / 2.0;
        int xi = (int)v0, yi = (int)v1, zi = (int)v2;
        if (xi>=0 && xi<XS && yi>=0 && yi<YS && zi>=0 && zi<ZS)
            mask[(xi*YS + yi)*ZS + zi] = 1;
    }
}

// ======== attn_fused32: offaw MFMA + softmax + 4x{desc, qv-prefetch, sampling, Wout, LN} ========
__global__ __launch_bounds__(256, 2)
void attn_fused(const float* __restrict__ q_in,
                const float* __restrict__ refpix,
                const unsigned short* __restrict__ Wbf,    // [320][128] bf16 (padded)
                const float* __restrict__ boff,
                const float* __restrict__ battw,
                const unsigned short* __restrict__ value,  // [NH][NVPIX][HD]
                const unsigned short* __restrict__ WoutBf, // [128][128] bf16
                const float* __restrict__ bout,
                const float* __restrict__ lng,
                const float* __restrict__ lnb,
                const unsigned char* __restrict__ mask,
                float* __restrict__ dout){
    const int nq0 = blockIdx.x * 32;
    const int t = threadIdx.x;
    __shared__ __align__(16) unsigned char smem[36384];
    unsigned short* Ob    = (unsigned short*)smem;
    unsigned char*  qbfB  = smem + 18432;
    unsigned char*  descB = smem + 18432;
    float*          out2  = (float*)(smem + 18432);
    unsigned char*  obfB  = smem + 30720;
    float*          bias  = (float*)(smem + 34816);
    float*          rp_s  = (float*)(smem + 35968);
    unsigned char*  mask_s= smem + 36224;
    float*          wredp = (float*)(smem + 36256);

    // ---- stage: q -> swizzled bf16, bias, rp, mask, zero obf pad rows ----
    #pragma unroll
    for (int i=0;i<4;i++){
        int idx = t + i*256;              // 1024 float4s = 32 rows x 32
        int row = idx >> 5, c4 = idx & 31;
        float4 qv = ((const float4*)(q_in + (size_t)(nq0+row)*CDIM))[c4];
        unsigned int pk0 = (unsigned int)f2b(qv.x) | ((unsigned int)f2b(qv.y)<<16);
        unsigned int pk1 = (unsigned int)f2b(qv.z) | ((unsigned int)f2b(qv.w)<<16);
        unsigned int bo = ((unsigned int)(row*256 + c4*8)) ^ (unsigned int)((row&7)<<4);
        *(unsigned int*)(qbfB + bo)     = pk0;
        *(unsigned int*)(qbfB + bo + 4) = pk1;
    }
    for (int i=t;i<288;i+=256) bias[i] = (i<192)? boff[i] : battw[i-192];
    ((unsigned int*)obfB)[512 + t] = 0;   // zero obf rows 8..15
    ((unsigned int*)obfB)[768 + t] = 0;
    if (t < 64) rp_s[t] = refpix[nq0*2 + t];
    if (t < 32) mask_s[t] = mask[nq0 + t];
    __syncthreads();

    // ---- offaw MFMA: 5 feature tiles x 2 query tiles x 4 K-steps per wave ----
    {
        const int w = t >> 6, lane = t & 63, lr = lane & 15, lg = lane >> 4;
        const int nt0 = w*5;
        f32x4 acc[5][2];
        #pragma unroll
        for (int j=0;j<5;j++){ acc[j][0]=(f32x4){0,0,0,0}; acc[j][1]=(f32x4){0,0,0,0}; }
        #pragma unroll
        for (int ks=0; ks<4; ++ks){
            s16x8 bf[2];
            #pragma unroll
            for (int qt=0;qt<2;qt++){
                int qrow = qt*16 + lr;
                unsigned int bo = ((unsigned int)(qrow*256 + ks*64 + lg*16)) ^ (unsigned int)((qrow&7)<<4);
                bf[qt] = *(const s16x8*)(qbfB + bo);
            }
            const unsigned short* wp = Wbf + (size_t)(nt0*16 + lr)*CDIM + ks*32 + lg*8;
            #pragma unroll
            for (int j=0;j<5;++j){
                s16x8 af = *(const s16x8*)(wp + j*16*CDIM);
                acc[j][0] = __builtin_amdgcn_mfma_f32_16x16x32_bf16(af, bf[0], acc[j][0], 0, 0, 0);
                acc[j][1] = __builtin_amdgcn_mfma_f32_16x16x32_bf16(af, bf[1], acc[j][1], 0, 0, 0);
            }
        }
        #pragma unroll
        for (int j=0;j<5;++j){
            int nt = nt0 + j;
            if (nt < 18){
                #pragma unroll
                for (int qt=0;qt<2;qt++){
                    int q = qt*16 + lr;
                    int base = (q>>3)*2304 + (q&7);
                    #pragma unroll
                    for (int r=0;r<4;++r){
                        int f = nt*16 + lg*4 + r;
                        Ob[base + f*8] = f2b(acc[j][qt][r] + bias[f]);
                    }
                }
            }
        }
    }
    __syncthreads();

    // ---- softmax: 32q x 8h = 256 tasks, one per thread ----
    {
        int q = t >> 3, h = t & 7;
        unsigned short* p = Ob + (q>>3)*2304 + (192 + h*12)*8 + (q&7);
        float e[12]; float m = -1e30f;
        #pragma unroll
        for (int i=0;i<12;i++){ e[i] = b2f(p[i*8]); m = fmaxf(m, e[i]); }
        float s = 0.f;
        #pragma unroll
        for (int i=0;i<12;i++){ e[i] = __expf(e[i]-m); s += e[i]; }
        float is = 1.f/s;
        #pragma unroll
        for (int i=0;i<12;i++) p[i*8] = f2b(e[i]*is);
    }
    __syncthreads();

    // ---- 4 sub-rounds of 8 queries ----
    for (int sr = 0; sr < 4; ++sr){
        const unsigned short* raw = Ob + sr*2304;
        const int nsr = nq0 + sr*8;

        // desc: 768 sample descriptors
        for (int idx = t; idx < 768; idx += 256){
            int q = idx & 7, hp = idx >> 3;
            int lp = hp % 12;
            float fw, fh; int Wl, Hl, st;
            if (lp < 4)      { fw=160.f; fh=48.f; Wl=160; Hl=48; st=0; }
            else if (lp < 8) { fw=80.f;  fh=24.f; Wl=80;  Hl=24; st=7680; }
            else             { fw=40.f;  fh=12.f; Wl=40;  Hl=12; st=9600; }
            float offx = b2f(raw[(hp*2)*8 + q]);
            float offy = b2f(raw[(hp*2+1)*8 + q]);
            float aw   = b2f(raw[(192+hp)*8 + q]);
            float x = rp_s[(sr*8+q)*2+0]*fw - 0.5f + offx;
            float y = rp_s[(sr*8+q)*2+1]*fh - 0.5f + offy;
            float x0f = floorf(x), y0f = floorf(y);
            float lx = x-x0f, ly = y-y0f;
            int x0 = (int)x0f, y0 = (int)y0f;
            bool x0ok = (x0>=0)&&(x0<Wl), x1ok=(x0+1>=0)&&(x0+1<Wl);
            bool y0ok = (y0>=0)&&(y0<Hl), y1ok=(y0+1>=0)&&(y0+1<Hl);
            float w00 = (x0ok&&y0ok)? (1.f-lx)*(1.f-ly)*aw : 0.f;
            float w01 = (x1ok&&y0ok)? lx*(1.f-ly)*aw       : 0.f;
            float w10 = (x0ok&&y1ok)? (1.f-lx)*ly*aw       : 0.f;
            float w11 = (x1ok&&y1ok)? lx*ly*aw             : 0.f;
            int yc0 = min(max(y0,0),Hl-1), yc1 = min(max(y0+1,0),Hl-1);
            int xc0 = min(max(x0,0),Wl-1), xc1 = min(max(x0+1,0),Wl-1);
            unsigned int rb0 = (unsigned int)(st + yc0*Wl), rb1 = (unsigned int)(st + yc1*Wl);
            uint4 d;
            d.x = (rb0+(unsigned int)xc0) | ((rb0+(unsigned int)xc1)<<16);
            d.y = (rb1+(unsigned int)xc0) | ((rb1+(unsigned int)xc1)<<16);
            d.z = (unsigned int)f2b(w00) | ((unsigned int)f2b(w01)<<16);
            d.w = (unsigned int)f2b(w10) | ((unsigned int)f2b(w11)<<16);
            *(uint4*)(descB + (((unsigned int)(idx ^ ((idx>>5)&7)))<<4)) = d;
        }
        __syncthreads();

        // qv prefetch: issue residual q loads now; consumed after Wout (hidden under sampling)
        float qv[4];
        {
            const int r = t & 127, qb = t >> 7;
            #pragma unroll
            for (int qi4=0;qi4<4;qi4++)
                qv[qi4] = q_in[(size_t)(nsr + qb*4 + qi4)*CDIM + r];
        }

        // sampling: 2 channels x 2 queries per thread, u32-offset gathers
        {
            const int cp = t & 7, hs = (t>>3) & 7, qgs = t >> 6;
            const unsigned int vbase = (unsigned int)hs*(NVPIX*HD*2) + (unsigned int)cp*4;
            const char* vb = (const char*)value;
            float av0x=0.f, av0y=0.f, av1x=0.f, av1y=0.f;
            #pragma unroll
            for (int lp=0; lp<12; ++lp){
                #pragma unroll
                for (int qi2=0; qi2<2; ++qi2){
                    int idx = (hs*12+lp)*8 + qgs*2 + qi2;
                    uint4 d = *(const uint4*)(descB + (((unsigned int)(idx ^ ((idx>>5)&7)))<<4));
                    unsigned int o00 = vbase + ((d.x & 0xffffu)<<5);
                    unsigned int o01 = vbase + ((d.x >> 16)<<5);
                    unsigned int o10 = vbase + ((d.y & 0xffffu)<<5);
                    unsigned int o11 = vbase + ((d.y >> 16)<<5);
                    unsigned int u00 = *(const unsigned int*)(vb + o00);
                    unsigned int u01 = *(const unsigned int*)(vb + o01);
                    unsigned int u10 = *(const unsigned int*)(vb + o10);
                    unsigned int u11 = *(const unsigned int*)(vb + o11);
                    float w00 = blo(d.z), w01 = bhi(d.z), w10 = blo(d.w), w11 = bhi(d.w);
                    float sx = blo(u00)*w00 + blo(u01)*w01 + blo(u10)*w10 + blo(u11)*w11;
                    float sy = bhi(u00)*w00 + bhi(u01)*w01 + bhi(u10)*w10 + bhi(u11)*w11;
                    if (qi2 == 0){ av0x += sx; av0y += sy; }
                    else         { av1x += sx; av1y += sy; }
                }
            }
            const int q0q = qgs*2;
            unsigned int pk0 = (unsigned int)f2b(av0x) | ((unsigned int)f2b(av0y)<<16);
            unsigned int pk1 = (unsigned int)f2b(av1x) | ((unsigned int)f2b(av1y)<<16);
            unsigned int bo0 = (unsigned int)(q0q*256 + hs*32 + cp*4)     ^ (unsigned int)((q0q&7)<<4);
            unsigned int bo1 = (unsigned int)((q0q+1)*256 + hs*32 + cp*4) ^ (unsigned int)(((q0q+1)&7)<<4);
            *(unsigned int*)(obfB + bo0) = pk0;
            *(unsigned int*)(obfB + bo1) = pk1;
        }
        __syncthreads();

        // Wout projection via MFMA, bout folded
        {
            const int w = t >> 6, lane = t & 63, lr = lane & 15, lg = lane >> 4;
            f32x4 a0 = (f32x4){0.f,0.f,0.f,0.f};
            f32x4 a1 = (f32x4){0.f,0.f,0.f,0.f};
            #pragma unroll
            for (int ks=0; ks<4; ++ks){
                unsigned int bo = (unsigned int)(lr*256 + ks*64 + lg*16) ^ (unsigned int)((lr&7)<<4);
                s16x8 bfrag = *(const s16x8*)(obfB + bo);
                const unsigned short* wp = WoutBf + (size_t)(w*32 + lr)*CDIM + ks*32 + lg*8;
                s16x8 af0 = *(const s16x8*)(wp);
                s16x8 af1 = *(const s16x8*)(wp + 16*CDIM);
                a0 = __builtin_amdgcn_mfma_f32_16x16x32_bf16(af0, bfrag, a0, 0, 0, 0);
                a1 = __builtin_amdgcn_mfma_f32_16x16x32_bf16(af1, bfrag, a1, 0, 0, 0);
            }
            if (lr < 8){
                int f0 = w*32 + lg*4;
                float4 b0 = *(const float4*)(bout + f0);
                float4 b1 = *(const float4*)(bout + f0 + 16);
                float4 v0, v1;
                v0.x = a0[0]+b0.x; v0.y = a0[1]+b0.y; v0.z = a0[2]+b0.z; v0.w = a0[3]+b0.w;
                v1.x = a1[0]+b1.x; v1.y = a1[1]+b1.y; v1.z = a1[2]+b1.z; v1.w = a1[3]+b1.w;
                *(float4*)(out2 + lr*CDIM + f0)      = v0;
                *(float4*)(out2 + lr*CDIM + f0 + 16) = v1;
            }
        }
        __syncthreads();

        // residual (prefetched qv) + single-pass LN + mask + store
        {
            const int r = t & 127;
            const int qb = t >> 7;
            const int wv = t >> 6;
            float hv[4], s1[4], s2[4];
            #pragma unroll
            for (int qi4=0;qi4<4;qi4++){
                hv[qi4] = qv[qi4] + out2[(qb*4+qi4)*CDIM + r];
                s1[qi4] = hv[qi4];
                s2[qi4] = hv[qi4]*hv[qi4];
            }
            #pragma unroll
            for (int off=32; off>0; off>>=1){
                #pragma unroll
                for (int qi4=0;qi4<4;qi4++){
                    s1[qi4] += __shfl_xor(s1[qi4], off, 64);
                    s2[qi4] += __shfl_xor(s2[qi4], off, 64);
                }
            }
            if ((t&63)==0){
                #pragma unroll
                for (int qi4=0;qi4<4;qi4++){
                    wredp[0*16 + wv*4 + qi4] = s1[qi4];
                    wredp[1*16 + wv*4 + qi4] = s2[qi4];
                }
            }
            __syncthreads();

            float res[4];
            const float g = lng[r], b = lnb[r];
            #pragma unroll
            for (int qi4=0;qi4<4;qi4++){
                float mu  = (wredp[0*16 + (qb*2)*4 + qi4] + wredp[0*16 + (qb*2+1)*4 + qi4]) * (1.f/128.f);
                float msq = (wredp[1*16 + (qb*2)*4 + qi4] + wredp[1*16 + (qb*2+1)*4 + qi4]) * (1.f/128.f);
                float var = msq - mu*mu;
                float nv  = (hv[qi4]-mu) * __frsqrt_rn(var + 1e-5f) * g + b;
                res[qi4] = mask_s[sr*8 + qb*4+qi4] ? nv : qv[qi4];
            }
            float4 o; o.x=res[0]; o.y=res[1]; o.z=res[2]; o.w=res[3];
            *(float4*)(dout + (size_t)r*NQ + nsr + qb*4) = o;
        }
        __syncthreads();   // out2/desc region + wredp safe for next sub-round
    }
}

extern "C" void kernel_launch(void* const* d_in, const int* in_sizes, int n_in,
                              void* d_out, int out_size, void* d_ws, size_t ws_size,
                              hipStream_t stream){
    const float* scene  = (const float*)d_in[0];
    const float* f0     = (const float*)d_in[1];
    const float* f1     = (const float*)d_in[2];
    const float* f2     = (const float*)d_in[3];
    const float* depth  = (const float*)d_in[4];
    const float* K      = (const float*)d_in[5];
    const float* E      = (const float*)d_in[6];
    const float* vorig  = (const float*)d_in[7];
    const float* refpix = (const float*)d_in[8];
    const float* Wv     = (const float*)d_in[9];
    const float* bv     = (const float*)d_in[10];
    const float* Woff   = (const float*)d_in[11];
    const float* boff   = (const float*)d_in[12];
    const float* Wattw  = (const float*)d_in[13];
    const float* battw  = (const float*)d_in[14];
    const float* Wout   = (const float*)d_in[15];
    const float* bout   = (const float*)d_in[16];
    const float* lng    = (const float*)d_in[17];
    const float* lnb    = (const float*)d_in[18];

    char* ws = (char*)d_ws;
    // invm(512) + mask(131072) + value(2580480) + Wbf(114688) + WvT(65536)
    double*         invm   = (double*)(ws);
    unsigned char*  mask   = (unsigned char*)(ws + 512);
    unsigned short* value  = (unsigned short*)(ws + 512 + 131072);
    unsigned short* Wbf    = (unsigned short*)(ws + 512 + 131072 + 2580480);
    unsigned short* WoutBf = Wbf + 40960;
    float*          WvT    = (float*)(ws + 512 + 131072 + 2580480 + 114688);

    hipMemsetAsync(mask, 0, NQ, stream);
    inv_kernel<<<289, 256, 0, stream>>>(K, E, invm, Woff, Wattw, Wout, Wv, Wbf, WvT);

    int nVal  = NVPIX/8;            // 1260
    int nMask = (NPIX+255)/256;     // 480
    prep2_kernel<<<nVal + nMask, 256, 0, stream>>>(nVal, f0, f1, f2, WvT, bv, value,
                                                   depth, invm, vorig, mask);
    attn_fused<<<NQ/32, 256, 0, stream>>>(scene, refpix, Wbf, boff, battw, value,
                                          WoutBf, bout, lng, lnb, mask,
                                          (float*)d_out);
}